// Round 11
// baseline (722.531 us; speedup 1.0000x reference)
//
#include <hip/hip_runtime.h>
#include <math.h>

// ---------------------------------------------------------------------------
// FraudGCN round 11: unroll-8 gather walks (latency-bound at occ 75%),
// 3-segment GEMM1 (X staged 2x), BN finalize fused into stats via
// completion counter. 15 dispatches.
// ---------------------------------------------------------------------------

typedef unsigned short u16;
typedef u16 us4 __attribute__((ext_vector_type(4)));
typedef short s8v __attribute__((ext_vector_type(8)));
typedef float f4v __attribute__((ext_vector_type(4)));

__device__ __forceinline__ float b2f(u16 u) {
  union { unsigned int i; float f; } v; v.i = ((unsigned int)u) << 16; return v.f;
}
__device__ __forceinline__ u16 f2b(float f) {
  union { float f; unsigned int i; } v; v.f = f;
  unsigned int u = v.i;
  return (u16)((u + 0x7fffu + ((u >> 16) & 1u)) >> 16);
}
__device__ __forceinline__ u16 f2h(float f) {
  union { _Float16 h; u16 u; } v; v.h = (_Float16)f; return v.u;
}
__device__ __forceinline__ float h2f(u16 u) {
  union { u16 u; _Float16 h; } v; v.u = u; return (float)v.h;
}

// ---------------- weight prep ----------------
struct WcastDesc { const float* W; u16* Wt; int K; int M; };
struct WPrep {
  WcastDesc d[5];
  const float *Wl2, *Wr2, *bl2, *Wf1, *bf1;
  u16 *Wc1t, *Wc2t;
  float* biasC;
};
__global__ __launch_bounds__(256) void k_wprep(WPrep a) {
  int y = blockIdx.y;
  int idx = blockIdx.x * 256 + threadIdx.x;
  if (y < 5) {
    WcastDesc de = a.d[y];
    int n = de.K * de.M;
    if (idx >= n) return;
    int c = idx / de.K, k = idx - c * de.K;
    de.Wt[idx] = f2b(de.W[(size_t)k * de.M + c]);
  } else {
    if (idx >= 4096) return;
    int m = idx >> 6, k = idx & 63;
    float s1 = 0.f, s2 = 0.f;
    for (int j = 0; j < 64; ++j) {
      float wf = a.Wf1[(size_t)(64 + j) * 64 + m];
      s1 += a.Wl2[k * 64 + j] * wf;
      s2 += a.Wr2[k * 64 + j] * wf;
    }
    a.Wc1t[m * 64 + k] = f2b(s1);
    a.Wc2t[m * 64 + k] = f2b(s2);
    if (k == 0) {
      float b = a.bf1[m];
      for (int j = 0; j < 64; ++j) b += a.bl2[j] * a.Wf1[(size_t)(64 + j) * 64 + m];
      a.biasC[m] = b;
    }
  }
}

// ---------------- CSR build ----------------
__global__ __launch_bounds__(256) void k_deg(const int* __restrict__ ei, int* __restrict__ deg, int E) {
  int e = blockIdx.x * blockDim.x + threadIdx.x;
  if (e < E) atomicAdd(&deg[ei[E + e]], 1);
}

__global__ __launch_bounds__(256) void k_scan1(const int* __restrict__ deg, int* __restrict__ row_ptr,
                                               int* __restrict__ bsum, int n) {
  __shared__ int sh[256];
  int tid = threadIdx.x;
  int i = blockIdx.x * 256 + tid;
  int v = (i < n) ? deg[i] : 0;
  sh[tid] = v;
  __syncthreads();
  for (int off = 1; off < 256; off <<= 1) {
    int t = (tid >= off) ? sh[tid - off] : 0;
    __syncthreads();
    sh[tid] += t;
    __syncthreads();
  }
  if (i < n) row_ptr[i] = sh[tid] - v;
  if (tid == 255) bsum[blockIdx.x] = sh[255];
}

__global__ __launch_bounds__(1024) void k_scan2(int* __restrict__ bsum, int* __restrict__ total, int nb) {
  __shared__ int sh[1024];
  int tid = threadIdx.x;
  int v = (tid < nb) ? bsum[tid] : 0;
  sh[tid] = v;
  __syncthreads();
  for (int off = 1; off < 1024; off <<= 1) {
    int t = (tid >= off) ? sh[tid - off] : 0;
    __syncthreads();
    sh[tid] += t;
    __syncthreads();
  }
  if (tid < nb) bsum[tid] = sh[tid] - v;
  if (tid == 1023) *total = sh[1023];
}

__global__ __launch_bounds__(256) void k_scan3(int* __restrict__ row_ptr, const int* __restrict__ bsum, int n) {
  int i = blockIdx.x * 256 + threadIdx.x;
  if (i < n) row_ptr[i] += bsum[blockIdx.x];
}

__global__ __launch_bounds__(256) void k_scatter(const int* __restrict__ ei, const int* __restrict__ row_ptr,
                                                 int* __restrict__ cursor, int* __restrict__ csr_src, int E) {
  int e = blockIdx.x * blockDim.x + threadIdx.x;
  if (e < E) {
    int d = ei[E + e];
    int pos = row_ptr[d] + atomicAdd(&cursor[d], 1);
    csr_src[pos] = ei[e];
  }
}

// ---------------- 3-segment GEMM (A staged once per triple) -----------------
struct Seg { const u16* Wt; u16* out; int ldout; const float* bias; int head; };
struct Segs6 { Seg s[6]; };
__global__ __launch_bounds__(256) void k_gemm_multi(const float* __restrict__ X, Segs6 sg,
                                                    const float* __restrict__ a_src1, const float* __restrict__ a_dst1,
                                                    float* __restrict__ es1, float* __restrict__ ed1, int Nrows) {
  __shared__ u16 As[64][40];
  __shared__ u16 Bs[3][64][40];
  int base = blockIdx.y * 3;
  int row0 = blockIdx.x * 64;
  int tid = threadIdx.x;
  int w = tid >> 6, lane = tid & 63;
  int lr = tid >> 2;
  int lseg = (tid & 3) * 8;
  f4v acc[3][4];
#pragma unroll
  for (int p = 0; p < 3; ++p)
#pragma unroll
    for (int nn = 0; nn < 4; ++nn) acc[p][nn] = (f4v){0.f, 0.f, 0.f, 0.f};
  int ar = (w << 4) + (lane & 15);
  int ak = (lane >> 4) << 3;

  for (int k0 = 0; k0 < 128; k0 += 32) {
    __syncthreads();
    int gr = row0 + lr;
    s8v av = {};
    if (gr < Nrows) {
      float4 lo = *reinterpret_cast<const float4*>(X + (size_t)gr * 128 + k0 + lseg);
      float4 hi = *reinterpret_cast<const float4*>(X + (size_t)gr * 128 + k0 + lseg + 4);
      av[0] = (short)f2b(lo.x); av[1] = (short)f2b(lo.y); av[2] = (short)f2b(lo.z); av[3] = (short)f2b(lo.w);
      av[4] = (short)f2b(hi.x); av[5] = (short)f2b(hi.y); av[6] = (short)f2b(hi.z); av[7] = (short)f2b(hi.w);
    }
    *reinterpret_cast<s8v*>(&As[lr][lseg]) = av;
#pragma unroll
    for (int p = 0; p < 3; ++p) {
      s8v bv = *reinterpret_cast<const s8v*>(sg.s[base + p].Wt + (size_t)lr * 128 + k0 + lseg);
      *reinterpret_cast<s8v*>(&Bs[p][lr][lseg]) = bv;
    }
    __syncthreads();
    s8v af = *reinterpret_cast<const s8v*>(&As[ar][ak]);
#pragma unroll
    for (int p = 0; p < 3; ++p) {
#pragma unroll
      for (int nn = 0; nn < 4; ++nn) {
        s8v bf = *reinterpret_cast<const s8v*>(&Bs[p][(nn << 4) + (lane & 15)][ak]);
        acc[p][nn] = __builtin_amdgcn_mfma_f32_16x16x32_bf16(af, bf, acc[p][nn], 0, 0, 0);
      }
    }
  }
  int r0 = row0 + (w << 4) + ((lane >> 4) << 2);
  int cc = lane & 15;
#pragma unroll
  for (int p = 0; p < 3; ++p) {
    Seg seg = sg.s[base + p];
#pragma unroll
    for (int nn = 0; nn < 4; ++nn) {
      int gc = (nn << 4) + cc;
      float bv = seg.bias ? seg.bias[gc] : 0.f;
#pragma unroll
      for (int j = 0; j < 4; ++j) {
        int gr = r0 + j;
        if (gr < Nrows) seg.out[(size_t)gr * seg.ldout + gc] = f2b(acc[p][nn][j] + bv);
      }
    }
    if (seg.head >= 0) {
      int s = seg.head;
      float pe[4] = {0.f, 0.f, 0.f, 0.f}, pd[4] = {0.f, 0.f, 0.f, 0.f};
#pragma unroll
      for (int nn = 0; nn < 4; ++nn) {
        int col = (nn << 4) + cc;
        float asv = a_src1[s * 64 + col];
        float adv = a_dst1[s * 64 + col];
#pragma unroll
        for (int j = 0; j < 4; ++j) {
          pe[j] += acc[p][nn][j] * asv;
          pd[j] += acc[p][nn][j] * adv;
        }
      }
#pragma unroll
      for (int off = 1; off < 16; off <<= 1) {
#pragma unroll
        for (int j = 0; j < 4; ++j) {
          pe[j] += __shfl_xor(pe[j], off, 64);
          pd[j] += __shfl_xor(pd[j], off, 64);
        }
      }
      if (cc == 0) {
#pragma unroll
        for (int j = 0; j < 4; ++j) {
          int gr = r0 + j;
          if (gr < Nrows) {
            es1[(size_t)gr * 4 + s] = pe[j];
            ed1[(size_t)gr * 4 + s] = pd[j];
          }
        }
      }
    }
  }
}

// ---------------- GAT2 GEMM: BN+ELU on A-load, es2/ed2 epilogue --------------
__global__ __launch_bounds__(256) void k_gemm_bn(const u16* __restrict__ A, const u16* __restrict__ Wt,
                                                 const float* __restrict__ sc, const float* __restrict__ sh,
                                                 const float* __restrict__ a_src2, const float* __restrict__ a_dst2,
                                                 u16* __restrict__ C, float* __restrict__ es2,
                                                 float* __restrict__ ed2, int Nrows) {
  __shared__ u16 As[64][40];
  __shared__ u16 Bs[64][40];
  int row0 = blockIdx.x * 64;
  int tid = threadIdx.x;
  int w = tid >> 6, lane = tid & 63;
  int lr = tid >> 2;
  int lseg = (tid & 3) * 8;
  f4v acc[4];
#pragma unroll
  for (int nn = 0; nn < 4; ++nn) acc[nn] = (f4v){0.f, 0.f, 0.f, 0.f};
  int ar = (w << 4) + (lane & 15);
  int ak = (lane >> 4) << 3;

  for (int k0 = 0; k0 < 256; k0 += 32) {
    __syncthreads();
    int gr = row0 + lr;
    s8v av = {};
    if (gr < Nrows) {
      av = *reinterpret_cast<const s8v*>(A + (size_t)gr * 256 + k0 + lseg);
#pragma unroll
      for (int j = 0; j < 8; ++j) {
        int c = k0 + lseg + j;
        float a = b2f((u16)av[j]) * sc[c] + sh[c];
        a = (a > 0.f) ? a : (__expf(a) - 1.f);
        av[j] = (short)f2b(a);
      }
    }
    *reinterpret_cast<s8v*>(&As[lr][lseg]) = av;
    s8v bv = *reinterpret_cast<const s8v*>(Wt + (size_t)lr * 256 + k0 + lseg);
    *reinterpret_cast<s8v*>(&Bs[lr][lseg]) = bv;
    __syncthreads();
    s8v af = *reinterpret_cast<const s8v*>(&As[ar][ak]);
#pragma unroll
    for (int nn = 0; nn < 4; ++nn) {
      s8v bf = *reinterpret_cast<const s8v*>(&Bs[(nn << 4) + (lane & 15)][ak]);
      acc[nn] = __builtin_amdgcn_mfma_f32_16x16x32_bf16(af, bf, acc[nn], 0, 0, 0);
    }
  }
  int r0 = row0 + (w << 4) + ((lane >> 4) << 2);
  int cc = lane & 15;
  float pe[4] = {0.f, 0.f, 0.f, 0.f}, pd[4] = {0.f, 0.f, 0.f, 0.f};
#pragma unroll
  for (int nn = 0; nn < 4; ++nn) {
    int gc = (nn << 4) + cc;
    float asv = a_src2[gc], adv = a_dst2[gc];
#pragma unroll
    for (int j = 0; j < 4; ++j) {
      float hv = acc[nn][j];
      pe[j] += hv * asv;
      pd[j] += hv * adv;
      int gr = r0 + j;
      if (gr < Nrows) C[(size_t)gr * 64 + gc] = f2b(hv);
    }
  }
#pragma unroll
  for (int off = 1; off < 16; off <<= 1) {
#pragma unroll
    for (int j = 0; j < 4; ++j) {
      pe[j] += __shfl_xor(pe[j], off, 64);
      pd[j] += __shfl_xor(pd[j], off, 64);
    }
  }
  if (cc == 0) {
#pragma unroll
    for (int j = 0; j < 4; ++j) {
      int gr = r0 + j;
      if (gr < Nrows) { es2[gr] = pe[j]; ed2[gr] = pd[j]; }
    }
  }
}

// ---------------- GAT softmax stats + fp16 alphas ----------------
__global__ __launch_bounds__(256) void k_gat_stats4(const float* __restrict__ es, const float* __restrict__ ed,
                                                    const int* __restrict__ row_ptr, const int* __restrict__ csr,
                                                    u16* __restrict__ alphaE, u16* __restrict__ alphaS, int n) {
  int wid = (blockIdx.x * blockDim.x + threadIdx.x) >> 6;
  int lane = threadIdx.x & 63;
  if (wid >= n) return;
  int start = row_ptr[wid];
  int deg = row_ptr[wid + 1] - start;
  int h = lane & 3, esl = lane >> 2;
  float edst = ed[(size_t)wid * 4 + h];

  float m = -1e30f, s = 0.f;
  for (int e = esl; e < deg + 1; e += 16) {
    int sn = (e < deg) ? csr[start + e] : wid;
    float v = es[(size_t)sn * 4 + h] + edst;
    v = (v >= 0.f) ? v : 0.2f * v;
    if (v > m) { s = s * __expf(m - v) + 1.f; m = v; }
    else s += __expf(v - m);
  }
#pragma unroll
  for (int off = 4; off < 64; off <<= 1) {
    float mo = __shfl_xor(m, off, 64);
    float so = __shfl_xor(s, off, 64);
    float M = fmaxf(m, mo);
    s = s * __expf(m - M) + so * __expf(mo - M);
    m = M;
  }
  float invS = 1.f / s;
  for (int e = esl; e < deg + 1; e += 16) {
    int sn = (e < deg) ? csr[start + e] : wid;
    float v = es[(size_t)sn * 4 + h] + edst;
    v = (v >= 0.f) ? v : 0.2f * v;
    u16 a = f2h(__expf(v - m) * invS);
    if (e < deg) alphaE[(size_t)(start + e) * 4 + h] = a;
    else alphaS[(size_t)wid * 4 + h] = a;
  }
}

__global__ __launch_bounds__(256) void k_gat_stats1(const float* __restrict__ es, const float* __restrict__ ed,
                                                    const int* __restrict__ row_ptr, const int* __restrict__ csr,
                                                    u16* __restrict__ alphaE, u16* __restrict__ alphaS, int n) {
  int wid = (blockIdx.x * blockDim.x + threadIdx.x) >> 6;
  int lane = threadIdx.x & 63;
  if (wid >= n) return;
  int start = row_ptr[wid];
  int deg = row_ptr[wid + 1] - start;
  float edst = ed[wid];
  float m = -1e30f, s = 0.f;
  for (int e = lane; e < deg + 1; e += 64) {
    int sn = (e < deg) ? csr[start + e] : wid;
    float v = es[sn] + edst;
    v = (v >= 0.f) ? v : 0.2f * v;
    if (v > m) { s = s * __expf(m - v) + 1.f; m = v; }
    else s += __expf(v - m);
  }
#pragma unroll
  for (int off = 1; off < 64; off <<= 1) {
    float mo = __shfl_xor(m, off, 64);
    float so = __shfl_xor(s, off, 64);
    float M = fmaxf(m, mo);
    s = s * __expf(m - M) + so * __expf(mo - M);
    m = M;
  }
  float invS = 1.f / s;
  for (int e = lane; e < deg + 1; e += 64) {
    int sn = (e < deg) ? csr[start + e] : wid;
    float v = es[sn] + edst;
    v = (v >= 0.f) ? v : 0.2f * v;
    u16 a = f2h(__expf(v - m) * invS);
    if (e < deg) alphaE[start + e] = a;
    else alphaS[wid] = a;
  }
}

// ---------------- merged GAT1 + SAGE1 aggregate (unroll 8) ------------------
__global__ __launch_bounds__(256) void k_agg_gs1(const u16* __restrict__ h1, const u16* __restrict__ xl,
                                                 const u16* __restrict__ xr, const u16* __restrict__ alphaE,
                                                 const u16* __restrict__ alphaS, const int* __restrict__ row_ptr,
                                                 const int* __restrict__ csr, const float* __restrict__ b1g,
                                                 u16* __restrict__ gb, u16* __restrict__ s1, int n) {
  int wid = (blockIdx.x * blockDim.x + threadIdx.x) >> 6;
  int lane = threadIdx.x & 63;
  if (wid >= n) return;
  int start = row_ptr[wid];
  int deg = row_ptr[wid + 1] - start;
  int hl = lane >> 4;

  float accG[4];
  float accS = 0.f;
  {
    float aS = h2f(alphaS[(size_t)wid * 4 + hl]);
    us4 hv = *(reinterpret_cast<const us4*>(h1 + (size_t)wid * 256) + lane);
#pragma unroll
    for (int j = 0; j < 4; ++j) accG[j] = aS * b2f(hv[j]);
  }

  int e = 0;
  for (; e + 8 <= deg; e += 8) {
    int sn[8];
    float al[8];
#pragma unroll
    for (int i = 0; i < 8; ++i) {
      sn[i] = csr[start + e + i];
      al[i] = h2f(alphaE[(size_t)(start + e + i) * 4 + hl]);
    }
    us4 hv[8];
    u16 xv[8];
#pragma unroll
    for (int i = 0; i < 8; ++i) {
      hv[i] = *(reinterpret_cast<const us4*>(h1 + (size_t)sn[i] * 256) + lane);
      xv[i] = xl[(size_t)sn[i] * 64 + lane];
    }
#pragma unroll
    for (int i = 0; i < 8; ++i) {
#pragma unroll
      for (int j = 0; j < 4; ++j) accG[j] += al[i] * b2f(hv[i][j]);
      accS += b2f(xv[i]);
    }
  }
  for (; e < deg; ++e) {
    int sn = csr[start + e];
    float al = h2f(alphaE[(size_t)(start + e) * 4 + hl]);
    us4 hv = *(reinterpret_cast<const us4*>(h1 + (size_t)sn * 256) + lane);
#pragma unroll
    for (int j = 0; j < 4; ++j) accG[j] += al * b2f(hv[j]);
    accS += b2f(xl[(size_t)sn * 64 + lane]);
  }

  int c0 = lane * 4;
#pragma unroll
  for (int j = 0; j < 4; ++j) gb[(size_t)wid * 256 + c0 + j] = f2b(accG[j] + b1g[c0 + j]);
  float inv = 1.f / fmaxf((float)deg, 1.f);
  s1[(size_t)wid * 64 + lane] = f2b(accS * inv + b2f(xr[(size_t)wid * 64 + lane]));
}

// ---------------- merged GAT2 + SAGE2 aggregate (unroll 8) ------------------
__global__ __launch_bounds__(256) void k_agg_gs2(const u16* __restrict__ h2, const u16* __restrict__ s1,
                                                 const u16* __restrict__ alphaE, const u16* __restrict__ alphaS,
                                                 const int* __restrict__ row_ptr, const int* __restrict__ csr,
                                                 const float* __restrict__ b2g, const float* __restrict__ scs,
                                                 const float* __restrict__ shs, u16* __restrict__ g2,
                                                 u16* __restrict__ sagg2, int n) {
  int wid = (blockIdx.x * blockDim.x + threadIdx.x) >> 6;
  int lane = threadIdx.x & 63;
  if (wid >= n) return;
  int start = row_ptr[wid];
  int deg = row_ptr[wid + 1] - start;
  float scv = scs[lane], shv = shs[lane];

  float accG = h2f(alphaS[wid]) * b2f(h2[(size_t)wid * 64 + lane]);
  float accS = 0.f;
  int e = 0;
  for (; e + 8 <= deg; e += 8) {
    int sn[8];
    float al[8];
#pragma unroll
    for (int i = 0; i < 8; ++i) {
      sn[i] = csr[start + e + i];
      al[i] = h2f(alphaE[start + e + i]);
    }
    u16 hv[8], sv[8];
#pragma unroll
    for (int i = 0; i < 8; ++i) {
      hv[i] = h2[(size_t)sn[i] * 64 + lane];
      sv[i] = s1[(size_t)sn[i] * 64 + lane];
    }
#pragma unroll
    for (int i = 0; i < 8; ++i) {
      accG += al[i] * b2f(hv[i]);
      accS += fmaxf(b2f(sv[i]) * scv + shv, 0.f);
    }
  }
  for (; e < deg; ++e) {
    int sn = csr[start + e];
    accG += h2f(alphaE[start + e]) * b2f(h2[(size_t)sn * 64 + lane]);
    accS += fmaxf(b2f(s1[(size_t)sn * 64 + lane]) * scv + shv, 0.f);
  }

  g2[(size_t)wid * 64 + lane] = f2b(accG + b2g[lane]);
  float inv = 1.f / fmaxf((float)deg, 1.f);
  sagg2[(size_t)wid * 64 + lane] = f2b(accS * inv);
}

// ---------------- BN stats (gb 256ch + s1 64ch) + fused finalize ------------
__global__ __launch_bounds__(256) void k_bn_stats_both(const u16* __restrict__ gb, const u16* __restrict__ s1,
                                                       float* __restrict__ statsG, float* __restrict__ statsS,
                                                       int* __restrict__ done,
                                                       const float* __restrict__ gG, const float* __restrict__ bG,
                                                       const float* __restrict__ gS, const float* __restrict__ bS,
                                                       float* __restrict__ scG, float* __restrict__ shG,
                                                       float* __restrict__ scS, float* __restrict__ shS, int n) {
  int tid = threadIdx.x;
  __shared__ float ls[256], lq[256];
  __shared__ int lastFlag;
  if (blockIdx.x < 256) {
    int c = tid;
    float s = 0.f, q = 0.f;
    for (int r = blockIdx.x; r < n; r += 256) {
      float v = b2f(gb[(size_t)r * 256 + c]);
      s += v;
      q += v * v;
    }
    atomicAdd(&statsG[c], s);
    atomicAdd(&statsG[256 + c], q);
  } else {
    int bx = blockIdx.x - 256;
    int c = tid & 63;
    int rsub = tid >> 6;
    float s = 0.f, q = 0.f;
    for (int r = bx * 4 + rsub; r < n; r += 256 * 4) {
      float v = b2f(s1[(size_t)r * 64 + c]);
      s += v;
      q += v * v;
    }
    ls[tid] = s; lq[tid] = q;
    __syncthreads();
    if (tid < 64) {
#pragma unroll
      for (int i = 1; i < 4; ++i) { s += ls[tid + i * 64]; q += lq[tid + i * 64]; }
      atomicAdd(&statsS[c], s);
      atomicAdd(&statsS[64 + c], q);
    }
  }
  // completion: last block computes scale/shift
  __threadfence();
  __syncthreads();
  if (tid == 0) lastFlag = (atomicAdd(done, 1) == gridDim.x - 1) ? 1 : 0;
  __syncthreads();
  if (lastFlag) {
    __threadfence();
    int c = tid;
    float invn = 1.f / (float)n;
    {
      float mu = statsG[c] * invn;
      float var = statsG[256 + c] * invn - mu * mu;
      float rs = rsqrtf(var + 1e-5f) * gG[c];
      scG[c] = rs;
      shG[c] = bG[c] - mu * rs;
    }
    if (c < 64) {
      float mu = statsS[c] * invn;
      float var = statsS[64 + c] * invn - mu * mu;
      float rs = rsqrtf(var + 1e-5f) * gS[c];
      scS[c] = rs;
      shS[c] = bS[c] - mu * rs;
    }
  }
}

// ---------------- final GEMM: 3 inputs (A3 gets BN+relu) + fused head --------
__global__ __launch_bounds__(256) void k_gemm_final(const u16* __restrict__ A1, const u16* __restrict__ W1,
                                                    const u16* __restrict__ A2, const u16* __restrict__ W2,
                                                    const u16* __restrict__ A3, const u16* __restrict__ W3,
                                                    const float* __restrict__ scS, const float* __restrict__ shS,
                                                    const float* __restrict__ biasC, const float* __restrict__ Wf2,
                                                    const float* __restrict__ bf2, float* __restrict__ out,
                                                    int Nrows) {
  __shared__ u16 As[64][40];
  __shared__ u16 Bs[64][40];
  int row0 = blockIdx.x * 64;
  int tid = threadIdx.x;
  int w = tid >> 6, lane = tid & 63;
  int lr = tid >> 2;
  int lseg = (tid & 3) * 8;
  f4v acc[4];
#pragma unroll
  for (int nn = 0; nn < 4; ++nn) acc[nn] = (f4v){0.f, 0.f, 0.f, 0.f};
  int ar = (w << 4) + (lane & 15);
  int ak = (lane >> 4) << 3;

  const u16* Aarr[3] = {A1, A2, A3};
  const u16* Warr[3] = {W1, W2, W3};
#pragma unroll
  for (int ph = 0; ph < 3; ++ph) {
    const u16* A = Aarr[ph];
    const u16* Wt = Warr[ph];
#pragma unroll
    for (int k0 = 0; k0 < 64; k0 += 32) {
      __syncthreads();
      int gr = row0 + lr;
      s8v av = {};
      if (gr < Nrows) {
        av = *reinterpret_cast<const s8v*>(A + (size_t)gr * 64 + k0 + lseg);
        if (ph == 2) {
#pragma unroll
          for (int j = 0; j < 8; ++j) {
            int c = k0 + lseg + j;
            float a = fmaxf(b2f((u16)av[j]) * scS[c] + shS[c], 0.f);
            av[j] = (short)f2b(a);
          }
        }
      }
      *reinterpret_cast<s8v*>(&As[lr][lseg]) = av;
      s8v bv = *reinterpret_cast<const s8v*>(Wt + (size_t)lr * 64 + k0 + lseg);
      *reinterpret_cast<s8v*>(&Bs[lr][lseg]) = bv;
      __syncthreads();
      s8v af = *reinterpret_cast<const s8v*>(&As[ar][ak]);
#pragma unroll
      for (int nn = 0; nn < 4; ++nn) {
        s8v bf = *reinterpret_cast<const s8v*>(&Bs[(nn << 4) + (lane & 15)][ak]);
        acc[nn] = __builtin_amdgcn_mfma_f32_16x16x32_bf16(af, bf, acc[nn], 0, 0, 0);
      }
    }
  }

  int r0 = row0 + (w << 4) + ((lane >> 4) << 2);
  int cc = lane & 15;
  float p0[4] = {0.f, 0.f, 0.f, 0.f}, p1[4] = {0.f, 0.f, 0.f, 0.f};
#pragma unroll
  for (int nn = 0; nn < 4; ++nn) {
    int col = (nn << 4) + cc;
    float bC = biasC[col];
    float w0 = Wf2[col * 2 + 0], w1 = Wf2[col * 2 + 1];
#pragma unroll
    for (int j = 0; j < 4; ++j) {
      float f = fmaxf(acc[nn][j] + bC, 0.f);
      p0[j] += f * w0;
      p1[j] += f * w1;
    }
  }
#pragma unroll
  for (int off = 1; off < 16; off <<= 1) {
#pragma unroll
    for (int j = 0; j < 4; ++j) {
      p0[j] += __shfl_xor(p0[j], off, 64);
      p1[j] += __shfl_xor(p1[j], off, 64);
    }
  }
  if (cc == 0) {
    float b0 = bf2[0], b1 = bf2[1];
#pragma unroll
    for (int j = 0; j < 4; ++j) {
      int gr = r0 + j;
      if (gr < Nrows) {
        out[(size_t)gr * 2 + 0] = p0[j] + b0;
        out[(size_t)gr * 2 + 1] = p1[j] + b1;
      }
    }
  }
}

// ---------------------------------------------------------------------------
extern "C" void kernel_launch(void* const* d_in, const int* in_sizes, int n_in,
                              void* d_out, int out_size, void* d_ws, size_t ws_size,
                              hipStream_t stream) {
  const float* x      = (const float*)d_in[0];
  const int*   ei     = (const int*)d_in[1];
  const float* W1g    = (const float*)d_in[2];
  const float* a_src1 = (const float*)d_in[3];
  const float* a_dst1 = (const float*)d_in[4];
  const float* b1g    = (const float*)d_in[5];
  const float* bn1g_g = (const float*)d_in[6];
  const float* bn1g_b = (const float*)d_in[7];
  const float* W2g    = (const float*)d_in[8];
  const float* a_src2 = (const float*)d_in[9];
  const float* a_dst2 = (const float*)d_in[10];
  const float* b2g    = (const float*)d_in[11];
  const float* Wl1    = (const float*)d_in[12];
  const float* bl1    = (const float*)d_in[13];
  const float* Wr1    = (const float*)d_in[14];
  const float* bn1s_g = (const float*)d_in[15];
  const float* bn1s_b = (const float*)d_in[16];
  const float* Wl2    = (const float*)d_in[17];
  const float* bl2    = (const float*)d_in[18];
  const float* Wr2    = (const float*)d_in[19];
  const float* Wf1    = (const float*)d_in[20];
  const float* bf1    = (const float*)d_in[21];
  const float* Wf2    = (const float*)d_in[22];
  const float* bf2    = (const float*)d_in[23];

  const int N = in_sizes[0] / 128;  // 100000
  const int E = in_sizes[1] / 2;    // 1600000

  char* ws = (char*)d_ws;
  size_t off = 0;
  auto alloc = [&](size_t bytes) -> void* {
    size_t o = (off + 255) & ~(size_t)255;
    off = o + bytes;
    return (void*)(ws + o);
  };

  u16* h1b   = (u16*)alloc((size_t)N * 256 * 2);   // sagg2b overlays after agg_gs1
  u16* gb    = (u16*)alloc((size_t)N * 256 * 2);
  u16* h2b   = (u16*)alloc((size_t)N * 64 * 2);
  u16* g2b   = (u16*)alloc((size_t)N * 64 * 2);
  u16* xlb   = (u16*)alloc((size_t)N * 64 * 2);
  u16* xrb   = (u16*)alloc((size_t)N * 64 * 2);
  u16* s1b   = (u16*)alloc((size_t)N * 64 * 2);
  float* es1 = (float*)alloc((size_t)N * 4 * 4);
  float* ed1 = (float*)alloc((size_t)N * 4 * 4);
  float* es2 = (float*)alloc((size_t)N * 4);
  float* ed2 = (float*)alloc((size_t)N * 4);
  u16* alphaE = (u16*)alloc((size_t)E * 4 * 2);
  u16* alphaS = (u16*)alloc((size_t)N * 4 * 2);
  int* deg     = (int*)alloc((size_t)N * 2 * 4);
  int* cursor  = deg + N;
  int* row_ptr = (int*)alloc((size_t)(N + 1) * 4);
  int* bsum    = (int*)alloc(1024 * 4);
  int* csr     = (int*)alloc((size_t)E * 4);
  float* statsG = (float*)alloc((512 + 128 + 4) * 4);  // + done counter
  float* statsS = statsG + 512;
  int* done    = (int*)(statsG + 640);
  float* scg   = (float*)alloc(256 * 4);
  float* shg   = (float*)alloc(256 * 4);
  float* scs   = (float*)alloc(64 * 4);
  float* shs   = (float*)alloc(64 * 4);
  float* biasC = (float*)alloc(64 * 4);
  u16* W1t  = (u16*)alloc(256 * 128 * 2);
  u16* W2t  = (u16*)alloc(64 * 256 * 2);
  u16* Wl1t = (u16*)alloc(64 * 128 * 2);
  u16* Wr1t = (u16*)alloc(64 * 128 * 2);
  u16* Wf1at= (u16*)alloc(64 * 64 * 2);
  u16* Wc1t = (u16*)alloc(64 * 64 * 2);
  u16* Wc2t = (u16*)alloc(64 * 64 * 2);
  u16* sagg2b = h1b;  // overlay: h1b dead after agg_gs1

  const int tb = 256;
  const int nwb = (N + 3) / 4;
  const int nsb = (N + 255) / 256;
  const int gx = (N + 63) / 64;

  // ---- CSR build + zeroing ----
  hipMemsetAsync(deg, 0, (size_t)N * 2 * 4, stream);
  hipMemsetAsync(statsG, 0, (512 + 128 + 4) * 4, stream);
  k_deg<<<(E + tb - 1) / tb, tb, 0, stream>>>(ei, deg, E);
  k_scan1<<<nsb, 256, 0, stream>>>(deg, row_ptr, bsum, N);
  k_scan2<<<1, 1024, 0, stream>>>(bsum, row_ptr + N, nsb);
  k_scan3<<<nsb, 256, 0, stream>>>(row_ptr, bsum, N);
  k_scatter<<<(E + tb - 1) / tb, tb, 0, stream>>>(ei, row_ptr, cursor, csr, E);

  // ---- weight prep ----
  WPrep wp;
  wp.d[0] = { W1g, W1t, 128, 256 };
  wp.d[1] = { W2g, W2t, 256, 64 };
  wp.d[2] = { Wl1, Wl1t, 128, 64 };
  wp.d[3] = { Wr1, Wr1t, 128, 64 };
  wp.d[4] = { Wf1, Wf1at, 64, 64 };
  wp.Wl2 = Wl2; wp.Wr2 = Wr2; wp.bl2 = bl2; wp.Wf1 = Wf1; wp.bf1 = bf1;
  wp.Wc1t = Wc1t; wp.Wc2t = Wc2t; wp.biasC = biasC;
  dim3 wgrid((128 * 256 + tb - 1) / tb, 6);
  k_wprep<<<wgrid, tb, 0, stream>>>(wp);

  // ---- 3-segment GEMM: (h1 heads 0-2 | head3,xl,xr); es1/ed1 fused ----
  Segs6 sg;
  sg.s[0] = { W1t,             h1b + 0,   256, nullptr, 0 };
  sg.s[1] = { W1t + 64 * 128,  h1b + 64,  256, nullptr, 1 };
  sg.s[2] = { W1t + 128 * 128, h1b + 128, 256, nullptr, 2 };
  sg.s[3] = { W1t + 192 * 128, h1b + 192, 256, nullptr, 3 };
  sg.s[4] = { Wl1t,            xlb, 64, nullptr, -1 };
  sg.s[5] = { Wr1t,            xrb, 64, bl1,     -1 };
  k_gemm_multi<<<dim3(gx, 2), 256, 0, stream>>>(x, sg, a_src1, a_dst1, es1, ed1, N);

  // ---- GAT1 stats, merged GAT1+SAGE1 aggregate, BN stats+finalize ----
  k_gat_stats4<<<nwb, 256, 0, stream>>>(es1, ed1, row_ptr, csr, alphaE, alphaS, N);
  k_agg_gs1<<<nwb, 256, 0, stream>>>(h1b, xlb, xrb, alphaE, alphaS, row_ptr, csr, b1g, gb, s1b, N);
  k_bn_stats_both<<<512, 256, 0, stream>>>(gb, s1b, statsG, statsS, done,
                                           bn1g_g, bn1g_b, bn1s_g, bn1s_b,
                                           scg, shg, scs, shs, N);

  // ---- GAT layer 2 (BN+ELU on A-load, es2/ed2 epilogue) ----
  k_gemm_bn<<<gx, 256, 0, stream>>>(gb, W2t, scg, shg, a_src2, a_dst2, h2b, es2, ed2, N);
  k_gat_stats1<<<nwb, 256, 0, stream>>>(es2, ed2, row_ptr, csr, alphaE, alphaS, N);
  k_agg_gs2<<<nwb, 256, 0, stream>>>(h2b, s1b, alphaE, alphaS, row_ptr, csr, b2g, scs, shs,
                                     g2b, sagg2b, N);

  // ---- final: fh = relu(g2@Wf1a + sagg2@Wc1 + relu(bn(s1))@Wc2 + biasC) @ Wf2
  k_gemm_final<<<gx, 256, 0, stream>>>(g2b, Wf1at, sagg2b, Wc1t, s1b, Wc2t,
                                       scs, shs, biasC, Wf2, bf2, (float*)d_out, N);
}

// Round 12
// 694.424 us; speedup vs baseline: 1.0405x; 1.0405x over previous
//
#include <hip/hip_runtime.h>
#include <math.h>

// ---------------------------------------------------------------------------
// FraudGCN round 12: revert round-11 regressions (unroll-8 -> unroll-4,
// 3-seg GEMM -> paired 2-seg). Keep BN stats+finalize fusion (completion
// counter; 'done' re-zeroed by memset each launch -> replay-safe).
// This is round-10's measured-best hot-loop config.
// ---------------------------------------------------------------------------

typedef unsigned short u16;
typedef u16 us4 __attribute__((ext_vector_type(4)));
typedef short s8v __attribute__((ext_vector_type(8)));
typedef float f4v __attribute__((ext_vector_type(4)));

__device__ __forceinline__ float b2f(u16 u) {
  union { unsigned int i; float f; } v; v.i = ((unsigned int)u) << 16; return v.f;
}
__device__ __forceinline__ u16 f2b(float f) {
  union { float f; unsigned int i; } v; v.f = f;
  unsigned int u = v.i;
  return (u16)((u + 0x7fffu + ((u >> 16) & 1u)) >> 16);
}
__device__ __forceinline__ u16 f2h(float f) {
  union { _Float16 h; u16 u; } v; v.h = (_Float16)f; return v.u;
}
__device__ __forceinline__ float h2f(u16 u) {
  union { u16 u; _Float16 h; } v; v.u = u; return (float)v.h;
}

// ---------------- weight prep ----------------
struct WcastDesc { const float* W; u16* Wt; int K; int M; };
struct WPrep {
  WcastDesc d[5];
  const float *Wl2, *Wr2, *bl2, *Wf1, *bf1;
  u16 *Wc1t, *Wc2t;
  float* biasC;
};
__global__ __launch_bounds__(256) void k_wprep(WPrep a) {
  int y = blockIdx.y;
  int idx = blockIdx.x * 256 + threadIdx.x;
  if (y < 5) {
    WcastDesc de = a.d[y];
    int n = de.K * de.M;
    if (idx >= n) return;
    int c = idx / de.K, k = idx - c * de.K;
    de.Wt[idx] = f2b(de.W[(size_t)k * de.M + c]);
  } else {
    if (idx >= 4096) return;
    int m = idx >> 6, k = idx & 63;
    float s1 = 0.f, s2 = 0.f;
    for (int j = 0; j < 64; ++j) {
      float wf = a.Wf1[(size_t)(64 + j) * 64 + m];
      s1 += a.Wl2[k * 64 + j] * wf;
      s2 += a.Wr2[k * 64 + j] * wf;
    }
    a.Wc1t[m * 64 + k] = f2b(s1);
    a.Wc2t[m * 64 + k] = f2b(s2);
    if (k == 0) {
      float b = a.bf1[m];
      for (int j = 0; j < 64; ++j) b += a.bl2[j] * a.Wf1[(size_t)(64 + j) * 64 + m];
      a.biasC[m] = b;
    }
  }
}

// ---------------- CSR build ----------------
__global__ __launch_bounds__(256) void k_deg(const int* __restrict__ ei, int* __restrict__ deg, int E) {
  int e = blockIdx.x * blockDim.x + threadIdx.x;
  if (e < E) atomicAdd(&deg[ei[E + e]], 1);
}

__global__ __launch_bounds__(256) void k_scan1(const int* __restrict__ deg, int* __restrict__ row_ptr,
                                               int* __restrict__ bsum, int n) {
  __shared__ int sh[256];
  int tid = threadIdx.x;
  int i = blockIdx.x * 256 + tid;
  int v = (i < n) ? deg[i] : 0;
  sh[tid] = v;
  __syncthreads();
  for (int off = 1; off < 256; off <<= 1) {
    int t = (tid >= off) ? sh[tid - off] : 0;
    __syncthreads();
    sh[tid] += t;
    __syncthreads();
  }
  if (i < n) row_ptr[i] = sh[tid] - v;
  if (tid == 255) bsum[blockIdx.x] = sh[255];
}

__global__ __launch_bounds__(1024) void k_scan2(int* __restrict__ bsum, int* __restrict__ total, int nb) {
  __shared__ int sh[1024];
  int tid = threadIdx.x;
  int v = (tid < nb) ? bsum[tid] : 0;
  sh[tid] = v;
  __syncthreads();
  for (int off = 1; off < 1024; off <<= 1) {
    int t = (tid >= off) ? sh[tid - off] : 0;
    __syncthreads();
    sh[tid] += t;
    __syncthreads();
  }
  if (tid < nb) bsum[tid] = sh[tid] - v;
  if (tid == 1023) *total = sh[1023];
}

__global__ __launch_bounds__(256) void k_scan3(int* __restrict__ row_ptr, const int* __restrict__ bsum, int n) {
  int i = blockIdx.x * 256 + threadIdx.x;
  if (i < n) row_ptr[i] += bsum[blockIdx.x];
}

__global__ __launch_bounds__(256) void k_scatter(const int* __restrict__ ei, const int* __restrict__ row_ptr,
                                                 int* __restrict__ cursor, int* __restrict__ csr_src, int E) {
  int e = blockIdx.x * blockDim.x + threadIdx.x;
  if (e < E) {
    int d = ei[E + e];
    int pos = row_ptr[d] + atomicAdd(&cursor[d], 1);
    csr_src[pos] = ei[e];
  }
}

// ---------------- paired-segment GEMM (A staged once per pair) --------------
struct Seg { const u16* Wt; u16* out; int ldout; const float* bias; int head; };
struct Segs6 { Seg s[6]; };
__global__ __launch_bounds__(256) void k_gemm_multi(const float* __restrict__ X, Segs6 sg,
                                                    const float* __restrict__ a_src1, const float* __restrict__ a_dst1,
                                                    float* __restrict__ es1, float* __restrict__ ed1, int Nrows) {
  Seg segA = sg.s[blockIdx.y * 2 + 0];
  Seg segB = sg.s[blockIdx.y * 2 + 1];
  __shared__ u16 As[64][40];
  __shared__ u16 Bs[2][64][40];
  int row0 = blockIdx.x * 64;
  int tid = threadIdx.x;
  int w = tid >> 6, lane = tid & 63;
  int lr = tid >> 2;
  int lseg = (tid & 3) * 8;
  f4v acc[2][4];
#pragma unroll
  for (int p = 0; p < 2; ++p)
#pragma unroll
    for (int nn = 0; nn < 4; ++nn) acc[p][nn] = (f4v){0.f, 0.f, 0.f, 0.f};
  int ar = (w << 4) + (lane & 15);
  int ak = (lane >> 4) << 3;

  for (int k0 = 0; k0 < 128; k0 += 32) {
    __syncthreads();
    int gr = row0 + lr;
    s8v av = {};
    if (gr < Nrows) {
      float4 lo = *reinterpret_cast<const float4*>(X + (size_t)gr * 128 + k0 + lseg);
      float4 hi = *reinterpret_cast<const float4*>(X + (size_t)gr * 128 + k0 + lseg + 4);
      av[0] = (short)f2b(lo.x); av[1] = (short)f2b(lo.y); av[2] = (short)f2b(lo.z); av[3] = (short)f2b(lo.w);
      av[4] = (short)f2b(hi.x); av[5] = (short)f2b(hi.y); av[6] = (short)f2b(hi.z); av[7] = (short)f2b(hi.w);
    }
    *reinterpret_cast<s8v*>(&As[lr][lseg]) = av;
    s8v bva = *reinterpret_cast<const s8v*>(segA.Wt + (size_t)lr * 128 + k0 + lseg);
    *reinterpret_cast<s8v*>(&Bs[0][lr][lseg]) = bva;
    s8v bvb = *reinterpret_cast<const s8v*>(segB.Wt + (size_t)lr * 128 + k0 + lseg);
    *reinterpret_cast<s8v*>(&Bs[1][lr][lseg]) = bvb;
    __syncthreads();
    s8v af = *reinterpret_cast<const s8v*>(&As[ar][ak]);
#pragma unroll
    for (int p = 0; p < 2; ++p) {
#pragma unroll
      for (int nn = 0; nn < 4; ++nn) {
        s8v bf = *reinterpret_cast<const s8v*>(&Bs[p][(nn << 4) + (lane & 15)][ak]);
        acc[p][nn] = __builtin_amdgcn_mfma_f32_16x16x32_bf16(af, bf, acc[p][nn], 0, 0, 0);
      }
    }
  }
  int r0 = row0 + (w << 4) + ((lane >> 4) << 2);
  int cc = lane & 15;
#pragma unroll
  for (int p = 0; p < 2; ++p) {
    Seg seg = p ? segB : segA;
#pragma unroll
    for (int nn = 0; nn < 4; ++nn) {
      int gc = (nn << 4) + cc;
      float bv = seg.bias ? seg.bias[gc] : 0.f;
#pragma unroll
      for (int j = 0; j < 4; ++j) {
        int gr = r0 + j;
        if (gr < Nrows) seg.out[(size_t)gr * seg.ldout + gc] = f2b(acc[p][nn][j] + bv);
      }
    }
    if (seg.head >= 0) {
      int s = seg.head;
      float pe[4] = {0.f, 0.f, 0.f, 0.f}, pd[4] = {0.f, 0.f, 0.f, 0.f};
#pragma unroll
      for (int nn = 0; nn < 4; ++nn) {
        int col = (nn << 4) + cc;
        float asv = a_src1[s * 64 + col];
        float adv = a_dst1[s * 64 + col];
#pragma unroll
        for (int j = 0; j < 4; ++j) {
          pe[j] += acc[p][nn][j] * asv;
          pd[j] += acc[p][nn][j] * adv;
        }
      }
#pragma unroll
      for (int off = 1; off < 16; off <<= 1) {
#pragma unroll
        for (int j = 0; j < 4; ++j) {
          pe[j] += __shfl_xor(pe[j], off, 64);
          pd[j] += __shfl_xor(pd[j], off, 64);
        }
      }
      if (cc == 0) {
#pragma unroll
        for (int j = 0; j < 4; ++j) {
          int gr = r0 + j;
          if (gr < Nrows) {
            es1[(size_t)gr * 4 + s] = pe[j];
            ed1[(size_t)gr * 4 + s] = pd[j];
          }
        }
      }
    }
  }
}

// ---------------- GAT2 GEMM: BN+ELU on A-load, es2/ed2 epilogue --------------
__global__ __launch_bounds__(256) void k_gemm_bn(const u16* __restrict__ A, const u16* __restrict__ Wt,
                                                 const float* __restrict__ sc, const float* __restrict__ sh,
                                                 const float* __restrict__ a_src2, const float* __restrict__ a_dst2,
                                                 u16* __restrict__ C, float* __restrict__ es2,
                                                 float* __restrict__ ed2, int Nrows) {
  __shared__ u16 As[64][40];
  __shared__ u16 Bs[64][40];
  int row0 = blockIdx.x * 64;
  int tid = threadIdx.x;
  int w = tid >> 6, lane = tid & 63;
  int lr = tid >> 2;
  int lseg = (tid & 3) * 8;
  f4v acc[4];
#pragma unroll
  for (int nn = 0; nn < 4; ++nn) acc[nn] = (f4v){0.f, 0.f, 0.f, 0.f};
  int ar = (w << 4) + (lane & 15);
  int ak = (lane >> 4) << 3;

  for (int k0 = 0; k0 < 256; k0 += 32) {
    __syncthreads();
    int gr = row0 + lr;
    s8v av = {};
    if (gr < Nrows) {
      av = *reinterpret_cast<const s8v*>(A + (size_t)gr * 256 + k0 + lseg);
#pragma unroll
      for (int j = 0; j < 8; ++j) {
        int c = k0 + lseg + j;
        float a = b2f((u16)av[j]) * sc[c] + sh[c];
        a = (a > 0.f) ? a : (__expf(a) - 1.f);
        av[j] = (short)f2b(a);
      }
    }
    *reinterpret_cast<s8v*>(&As[lr][lseg]) = av;
    s8v bv = *reinterpret_cast<const s8v*>(Wt + (size_t)lr * 256 + k0 + lseg);
    *reinterpret_cast<s8v*>(&Bs[lr][lseg]) = bv;
    __syncthreads();
    s8v af = *reinterpret_cast<const s8v*>(&As[ar][ak]);
#pragma unroll
    for (int nn = 0; nn < 4; ++nn) {
      s8v bf = *reinterpret_cast<const s8v*>(&Bs[(nn << 4) + (lane & 15)][ak]);
      acc[nn] = __builtin_amdgcn_mfma_f32_16x16x32_bf16(af, bf, acc[nn], 0, 0, 0);
    }
  }
  int r0 = row0 + (w << 4) + ((lane >> 4) << 2);
  int cc = lane & 15;
  float pe[4] = {0.f, 0.f, 0.f, 0.f}, pd[4] = {0.f, 0.f, 0.f, 0.f};
#pragma unroll
  for (int nn = 0; nn < 4; ++nn) {
    int gc = (nn << 4) + cc;
    float asv = a_src2[gc], adv = a_dst2[gc];
#pragma unroll
    for (int j = 0; j < 4; ++j) {
      float hv = acc[nn][j];
      pe[j] += hv * asv;
      pd[j] += hv * adv;
      int gr = r0 + j;
      if (gr < Nrows) C[(size_t)gr * 64 + gc] = f2b(hv);
    }
  }
#pragma unroll
  for (int off = 1; off < 16; off <<= 1) {
#pragma unroll
    for (int j = 0; j < 4; ++j) {
      pe[j] += __shfl_xor(pe[j], off, 64);
      pd[j] += __shfl_xor(pd[j], off, 64);
    }
  }
  if (cc == 0) {
#pragma unroll
    for (int j = 0; j < 4; ++j) {
      int gr = r0 + j;
      if (gr < Nrows) { es2[gr] = pe[j]; ed2[gr] = pd[j]; }
    }
  }
}

// ---------------- GAT softmax stats + fp16 alphas ----------------
__global__ __launch_bounds__(256) void k_gat_stats4(const float* __restrict__ es, const float* __restrict__ ed,
                                                    const int* __restrict__ row_ptr, const int* __restrict__ csr,
                                                    u16* __restrict__ alphaE, u16* __restrict__ alphaS, int n) {
  int wid = (blockIdx.x * blockDim.x + threadIdx.x) >> 6;
  int lane = threadIdx.x & 63;
  if (wid >= n) return;
  int start = row_ptr[wid];
  int deg = row_ptr[wid + 1] - start;
  int h = lane & 3, esl = lane >> 2;
  float edst = ed[(size_t)wid * 4 + h];

  float m = -1e30f, s = 0.f;
  for (int e = esl; e < deg + 1; e += 16) {
    int sn = (e < deg) ? csr[start + e] : wid;
    float v = es[(size_t)sn * 4 + h] + edst;
    v = (v >= 0.f) ? v : 0.2f * v;
    if (v > m) { s = s * __expf(m - v) + 1.f; m = v; }
    else s += __expf(v - m);
  }
#pragma unroll
  for (int off = 4; off < 64; off <<= 1) {
    float mo = __shfl_xor(m, off, 64);
    float so = __shfl_xor(s, off, 64);
    float M = fmaxf(m, mo);
    s = s * __expf(m - M) + so * __expf(mo - M);
    m = M;
  }
  float invS = 1.f / s;
  for (int e = esl; e < deg + 1; e += 16) {
    int sn = (e < deg) ? csr[start + e] : wid;
    float v = es[(size_t)sn * 4 + h] + edst;
    v = (v >= 0.f) ? v : 0.2f * v;
    u16 a = f2h(__expf(v - m) * invS);
    if (e < deg) alphaE[(size_t)(start + e) * 4 + h] = a;
    else alphaS[(size_t)wid * 4 + h] = a;
  }
}

__global__ __launch_bounds__(256) void k_gat_stats1(const float* __restrict__ es, const float* __restrict__ ed,
                                                    const int* __restrict__ row_ptr, const int* __restrict__ csr,
                                                    u16* __restrict__ alphaE, u16* __restrict__ alphaS, int n) {
  int wid = (blockIdx.x * blockDim.x + threadIdx.x) >> 6;
  int lane = threadIdx.x & 63;
  if (wid >= n) return;
  int start = row_ptr[wid];
  int deg = row_ptr[wid + 1] - start;
  float edst = ed[wid];
  float m = -1e30f, s = 0.f;
  for (int e = lane; e < deg + 1; e += 64) {
    int sn = (e < deg) ? csr[start + e] : wid;
    float v = es[sn] + edst;
    v = (v >= 0.f) ? v : 0.2f * v;
    if (v > m) { s = s * __expf(m - v) + 1.f; m = v; }
    else s += __expf(v - m);
  }
#pragma unroll
  for (int off = 1; off < 64; off <<= 1) {
    float mo = __shfl_xor(m, off, 64);
    float so = __shfl_xor(s, off, 64);
    float M = fmaxf(m, mo);
    s = s * __expf(m - M) + so * __expf(mo - M);
    m = M;
  }
  float invS = 1.f / s;
  for (int e = lane; e < deg + 1; e += 64) {
    int sn = (e < deg) ? csr[start + e] : wid;
    float v = es[sn] + edst;
    v = (v >= 0.f) ? v : 0.2f * v;
    u16 a = f2h(__expf(v - m) * invS);
    if (e < deg) alphaE[start + e] = a;
    else alphaS[wid] = a;
  }
}

// ---------------- merged GAT1 + SAGE1 aggregate (unroll 4) ------------------
__global__ __launch_bounds__(256) void k_agg_gs1(const u16* __restrict__ h1, const u16* __restrict__ xl,
                                                 const u16* __restrict__ xr, const u16* __restrict__ alphaE,
                                                 const u16* __restrict__ alphaS, const int* __restrict__ row_ptr,
                                                 const int* __restrict__ csr, const float* __restrict__ b1g,
                                                 u16* __restrict__ gb, u16* __restrict__ s1, int n) {
  int wid = (blockIdx.x * blockDim.x + threadIdx.x) >> 6;
  int lane = threadIdx.x & 63;
  if (wid >= n) return;
  int start = row_ptr[wid];
  int deg = row_ptr[wid + 1] - start;
  int hl = lane >> 4;

  float accG[4];
  float accS = 0.f;
  {
    float aS = h2f(alphaS[(size_t)wid * 4 + hl]);
    us4 hv = *(reinterpret_cast<const us4*>(h1 + (size_t)wid * 256) + lane);
#pragma unroll
    for (int j = 0; j < 4; ++j) accG[j] = aS * b2f(hv[j]);
  }

  int e = 0;
  for (; e + 4 <= deg; e += 4) {
    int sn[4];
    float al[4];
#pragma unroll
    for (int i = 0; i < 4; ++i) {
      sn[i] = csr[start + e + i];
      al[i] = h2f(alphaE[(size_t)(start + e + i) * 4 + hl]);
    }
#pragma unroll
    for (int i = 0; i < 4; ++i) {
      us4 hv = *(reinterpret_cast<const us4*>(h1 + (size_t)sn[i] * 256) + lane);
#pragma unroll
      for (int j = 0; j < 4; ++j) accG[j] += al[i] * b2f(hv[j]);
      accS += b2f(xl[(size_t)sn[i] * 64 + lane]);
    }
  }
  for (; e < deg; ++e) {
    int sn = csr[start + e];
    float al = h2f(alphaE[(size_t)(start + e) * 4 + hl]);
    us4 hv = *(reinterpret_cast<const us4*>(h1 + (size_t)sn * 256) + lane);
#pragma unroll
    for (int j = 0; j < 4; ++j) accG[j] += al * b2f(hv[j]);
    accS += b2f(xl[(size_t)sn * 64 + lane]);
  }

  int c0 = lane * 4;
#pragma unroll
  for (int j = 0; j < 4; ++j) gb[(size_t)wid * 256 + c0 + j] = f2b(accG[j] + b1g[c0 + j]);
  float inv = 1.f / fmaxf((float)deg, 1.f);
  s1[(size_t)wid * 64 + lane] = f2b(accS * inv + b2f(xr[(size_t)wid * 64 + lane]));
}

// ---------------- merged GAT2 + SAGE2 aggregate (unroll 4) ------------------
__global__ __launch_bounds__(256) void k_agg_gs2(const u16* __restrict__ h2, const u16* __restrict__ s1,
                                                 const u16* __restrict__ alphaE, const u16* __restrict__ alphaS,
                                                 const int* __restrict__ row_ptr, const int* __restrict__ csr,
                                                 const float* __restrict__ b2g, const float* __restrict__ scs,
                                                 const float* __restrict__ shs, u16* __restrict__ g2,
                                                 u16* __restrict__ sagg2, int n) {
  int wid = (blockIdx.x * blockDim.x + threadIdx.x) >> 6;
  int lane = threadIdx.x & 63;
  if (wid >= n) return;
  int start = row_ptr[wid];
  int deg = row_ptr[wid + 1] - start;
  float scv = scs[lane], shv = shs[lane];

  float accG = h2f(alphaS[wid]) * b2f(h2[(size_t)wid * 64 + lane]);
  float accS = 0.f;
  int e = 0;
  for (; e + 4 <= deg; e += 4) {
    int sn[4];
    float al[4];
#pragma unroll
    for (int i = 0; i < 4; ++i) {
      sn[i] = csr[start + e + i];
      al[i] = h2f(alphaE[start + e + i]);
    }
#pragma unroll
    for (int i = 0; i < 4; ++i) {
      accG += al[i] * b2f(h2[(size_t)sn[i] * 64 + lane]);
      accS += fmaxf(b2f(s1[(size_t)sn[i] * 64 + lane]) * scv + shv, 0.f);
    }
  }
  for (; e < deg; ++e) {
    int sn = csr[start + e];
    accG += h2f(alphaE[start + e]) * b2f(h2[(size_t)sn * 64 + lane]);
    accS += fmaxf(b2f(s1[(size_t)sn * 64 + lane]) * scv + shv, 0.f);
  }

  g2[(size_t)wid * 64 + lane] = f2b(accG + b2g[lane]);
  float inv = 1.f / fmaxf((float)deg, 1.f);
  sagg2[(size_t)wid * 64 + lane] = f2b(accS * inv);
}

// ---------------- BN stats (gb 256ch + s1 64ch) + fused finalize ------------
__global__ __launch_bounds__(256) void k_bn_stats_both(const u16* __restrict__ gb, const u16* __restrict__ s1,
                                                       float* __restrict__ statsG, float* __restrict__ statsS,
                                                       int* __restrict__ done,
                                                       const float* __restrict__ gG, const float* __restrict__ bG,
                                                       const float* __restrict__ gS, const float* __restrict__ bS,
                                                       float* __restrict__ scG, float* __restrict__ shG,
                                                       float* __restrict__ scS, float* __restrict__ shS, int n) {
  int tid = threadIdx.x;
  __shared__ float ls[256], lq[256];
  __shared__ int lastFlag;
  if (blockIdx.x < 256) {
    int c = tid;
    float s = 0.f, q = 0.f;
    for (int r = blockIdx.x; r < n; r += 256) {
      float v = b2f(gb[(size_t)r * 256 + c]);
      s += v;
      q += v * v;
    }
    atomicAdd(&statsG[c], s);
    atomicAdd(&statsG[256 + c], q);
  } else {
    int bx = blockIdx.x - 256;
    int c = tid & 63;
    int rsub = tid >> 6;
    float s = 0.f, q = 0.f;
    for (int r = bx * 4 + rsub; r < n; r += 256 * 4) {
      float v = b2f(s1[(size_t)r * 64 + c]);
      s += v;
      q += v * v;
    }
    ls[tid] = s; lq[tid] = q;
    __syncthreads();
    if (tid < 64) {
#pragma unroll
      for (int i = 1; i < 4; ++i) { s += ls[tid + i * 64]; q += lq[tid + i * 64]; }
      atomicAdd(&statsS[c], s);
      atomicAdd(&statsS[64 + c], q);
    }
  }
  __threadfence();
  __syncthreads();
  if (tid == 0) lastFlag = (atomicAdd(done, 1) == gridDim.x - 1) ? 1 : 0;
  __syncthreads();
  if (lastFlag) {
    __threadfence();
    int c = tid;
    float invn = 1.f / (float)n;
    {
      float mu = statsG[c] * invn;
      float var = statsG[256 + c] * invn - mu * mu;
      float rs = rsqrtf(var + 1e-5f) * gG[c];
      scG[c] = rs;
      shG[c] = bG[c] - mu * rs;
    }
    if (c < 64) {
      float mu = statsS[c] * invn;
      float var = statsS[64 + c] * invn - mu * mu;
      float rs = rsqrtf(var + 1e-5f) * gS[c];
      scS[c] = rs;
      shS[c] = bS[c] - mu * rs;
    }
  }
}

// ---------------- final GEMM: 3 inputs (A3 gets BN+relu) + fused head --------
__global__ __launch_bounds__(256) void k_gemm_final(const u16* __restrict__ A1, const u16* __restrict__ W1,
                                                    const u16* __restrict__ A2, const u16* __restrict__ W2,
                                                    const u16* __restrict__ A3, const u16* __restrict__ W3,
                                                    const float* __restrict__ scS, const float* __restrict__ shS,
                                                    const float* __restrict__ biasC, const float* __restrict__ Wf2,
                                                    const float* __restrict__ bf2, float* __restrict__ out,
                                                    int Nrows) {
  __shared__ u16 As[64][40];
  __shared__ u16 Bs[64][40];
  int row0 = blockIdx.x * 64;
  int tid = threadIdx.x;
  int w = tid >> 6, lane = tid & 63;
  int lr = tid >> 2;
  int lseg = (tid & 3) * 8;
  f4v acc[4];
#pragma unroll
  for (int nn = 0; nn < 4; ++nn) acc[nn] = (f4v){0.f, 0.f, 0.f, 0.f};
  int ar = (w << 4) + (lane & 15);
  int ak = (lane >> 4) << 3;

  const u16* Aarr[3] = {A1, A2, A3};
  const u16* Warr[3] = {W1, W2, W3};
#pragma unroll
  for (int ph = 0; ph < 3; ++ph) {
    const u16* A = Aarr[ph];
    const u16* Wt = Warr[ph];
#pragma unroll
    for (int k0 = 0; k0 < 64; k0 += 32) {
      __syncthreads();
      int gr = row0 + lr;
      s8v av = {};
      if (gr < Nrows) {
        av = *reinterpret_cast<const s8v*>(A + (size_t)gr * 64 + k0 + lseg);
        if (ph == 2) {
#pragma unroll
          for (int j = 0; j < 8; ++j) {
            int c = k0 + lseg + j;
            float a = fmaxf(b2f((u16)av[j]) * scS[c] + shS[c], 0.f);
            av[j] = (short)f2b(a);
          }
        }
      }
      *reinterpret_cast<s8v*>(&As[lr][lseg]) = av;
      s8v bv = *reinterpret_cast<const s8v*>(Wt + (size_t)lr * 64 + k0 + lseg);
      *reinterpret_cast<s8v*>(&Bs[lr][lseg]) = bv;
      __syncthreads();
      s8v af = *reinterpret_cast<const s8v*>(&As[ar][ak]);
#pragma unroll
      for (int nn = 0; nn < 4; ++nn) {
        s8v bf = *reinterpret_cast<const s8v*>(&Bs[(nn << 4) + (lane & 15)][ak]);
        acc[nn] = __builtin_amdgcn_mfma_f32_16x16x32_bf16(af, bf, acc[nn], 0, 0, 0);
      }
    }
  }

  int r0 = row0 + (w << 4) + ((lane >> 4) << 2);
  int cc = lane & 15;
  float p0[4] = {0.f, 0.f, 0.f, 0.f}, p1[4] = {0.f, 0.f, 0.f, 0.f};
#pragma unroll
  for (int nn = 0; nn < 4; ++nn) {
    int col = (nn << 4) + cc;
    float bC = biasC[col];
    float w0 = Wf2[col * 2 + 0], w1 = Wf2[col * 2 + 1];
#pragma unroll
    for (int j = 0; j < 4; ++j) {
      float f = fmaxf(acc[nn][j] + bC, 0.f);
      p0[j] += f * w0;
      p1[j] += f * w1;
    }
  }
#pragma unroll
  for (int off = 1; off < 16; off <<= 1) {
#pragma unroll
    for (int j = 0; j < 4; ++j) {
      p0[j] += __shfl_xor(p0[j], off, 64);
      p1[j] += __shfl_xor(p1[j], off, 64);
    }
  }
  if (cc == 0) {
    float b0 = bf2[0], b1 = bf2[1];
#pragma unroll
    for (int j = 0; j < 4; ++j) {
      int gr = r0 + j;
      if (gr < Nrows) {
        out[(size_t)gr * 2 + 0] = p0[j] + b0;
        out[(size_t)gr * 2 + 1] = p1[j] + b1;
      }
    }
  }
}

// ---------------------------------------------------------------------------
extern "C" void kernel_launch(void* const* d_in, const int* in_sizes, int n_in,
                              void* d_out, int out_size, void* d_ws, size_t ws_size,
                              hipStream_t stream) {
  const float* x      = (const float*)d_in[0];
  const int*   ei     = (const int*)d_in[1];
  const float* W1g    = (const float*)d_in[2];
  const float* a_src1 = (const float*)d_in[3];
  const float* a_dst1 = (const float*)d_in[4];
  const float* b1g    = (const float*)d_in[5];
  const float* bn1g_g = (const float*)d_in[6];
  const float* bn1g_b = (const float*)d_in[7];
  const float* W2g    = (const float*)d_in[8];
  const float* a_src2 = (const float*)d_in[9];
  const float* a_dst2 = (const float*)d_in[10];
  const float* b2g    = (const float*)d_in[11];
  const float* Wl1    = (const float*)d_in[12];
  const float* bl1    = (const float*)d_in[13];
  const float* Wr1    = (const float*)d_in[14];
  const float* bn1s_g = (const float*)d_in[15];
  const float* bn1s_b = (const float*)d_in[16];
  const float* Wl2    = (const float*)d_in[17];
  const float* bl2    = (const float*)d_in[18];
  const float* Wr2    = (const float*)d_in[19];
  const float* Wf1    = (const float*)d_in[20];
  const float* bf1    = (const float*)d_in[21];
  const float* Wf2    = (const float*)d_in[22];
  const float* bf2    = (const float*)d_in[23];

  const int N = in_sizes[0] / 128;  // 100000
  const int E = in_sizes[1] / 2;    // 1600000

  char* ws = (char*)d_ws;
  size_t off = 0;
  auto alloc = [&](size_t bytes) -> void* {
    size_t o = (off + 255) & ~(size_t)255;
    off = o + bytes;
    return (void*)(ws + o);
  };

  u16* h1b   = (u16*)alloc((size_t)N * 256 * 2);   // sagg2b overlays after agg_gs1
  u16* gb    = (u16*)alloc((size_t)N * 256 * 2);
  u16* h2b   = (u16*)alloc((size_t)N * 64 * 2);
  u16* g2b   = (u16*)alloc((size_t)N * 64 * 2);
  u16* xlb   = (u16*)alloc((size_t)N * 64 * 2);
  u16* xrb   = (u16*)alloc((size_t)N * 64 * 2);
  u16* s1b   = (u16*)alloc((size_t)N * 64 * 2);
  float* es1 = (float*)alloc((size_t)N * 4 * 4);
  float* ed1 = (float*)alloc((size_t)N * 4 * 4);
  float* es2 = (float*)alloc((size_t)N * 4);
  float* ed2 = (float*)alloc((size_t)N * 4);
  u16* alphaE = (u16*)alloc((size_t)E * 4 * 2);
  u16* alphaS = (u16*)alloc((size_t)N * 4 * 2);
  int* deg     = (int*)alloc((size_t)N * 2 * 4);
  int* cursor  = deg + N;
  int* row_ptr = (int*)alloc((size_t)(N + 1) * 4);
  int* bsum    = (int*)alloc(1024 * 4);
  int* csr     = (int*)alloc((size_t)E * 4);
  float* statsG = (float*)alloc((512 + 128 + 4) * 4);  // + done counter
  float* statsS = statsG + 512;
  int* done    = (int*)(statsG + 640);
  float* scg   = (float*)alloc(256 * 4);
  float* shg   = (float*)alloc(256 * 4);
  float* scs   = (float*)alloc(64 * 4);
  float* shs   = (float*)alloc(64 * 4);
  float* biasC = (float*)alloc(64 * 4);
  u16* W1t  = (u16*)alloc(256 * 128 * 2);
  u16* W2t  = (u16*)alloc(64 * 256 * 2);
  u16* Wl1t = (u16*)alloc(64 * 128 * 2);
  u16* Wr1t = (u16*)alloc(64 * 128 * 2);
  u16* Wf1at= (u16*)alloc(64 * 64 * 2);
  u16* Wc1t = (u16*)alloc(64 * 64 * 2);
  u16* Wc2t = (u16*)alloc(64 * 64 * 2);
  u16* sagg2b = h1b;  // overlay: h1b dead after agg_gs1

  const int tb = 256;
  const int nwb = (N + 3) / 4;
  const int nsb = (N + 255) / 256;
  const int gx = (N + 63) / 64;

  // ---- CSR build + zeroing ----
  hipMemsetAsync(deg, 0, (size_t)N * 2 * 4, stream);
  hipMemsetAsync(statsG, 0, (512 + 128 + 4) * 4, stream);
  k_deg<<<(E + tb - 1) / tb, tb, 0, stream>>>(ei, deg, E);
  k_scan1<<<nsb, 256, 0, stream>>>(deg, row_ptr, bsum, N);
  k_scan2<<<1, 1024, 0, stream>>>(bsum, row_ptr + N, nsb);
  k_scan3<<<nsb, 256, 0, stream>>>(row_ptr, bsum, N);
  k_scatter<<<(E + tb - 1) / tb, tb, 0, stream>>>(ei, row_ptr, cursor, csr, E);

  // ---- weight prep ----
  WPrep wp;
  wp.d[0] = { W1g, W1t, 128, 256 };
  wp.d[1] = { W2g, W2t, 256, 64 };
  wp.d[2] = { Wl1, Wl1t, 128, 64 };
  wp.d[3] = { Wr1, Wr1t, 128, 64 };
  wp.d[4] = { Wf1, Wf1at, 64, 64 };
  wp.Wl2 = Wl2; wp.Wr2 = Wr2; wp.bl2 = bl2; wp.Wf1 = Wf1; wp.bf1 = bf1;
  wp.Wc1t = Wc1t; wp.Wc2t = Wc2t; wp.biasC = biasC;
  dim3 wgrid((128 * 256 + tb - 1) / tb, 6);
  k_wprep<<<wgrid, tb, 0, stream>>>(wp);

  // ---- paired-segment GEMM: (h1 heads 0-1 | 2-3 | xl,xr); es1/ed1 fused ----
  Segs6 sg;
  sg.s[0] = { W1t,             h1b + 0,   256, nullptr, 0 };
  sg.s[1] = { W1t + 64 * 128,  h1b + 64,  256, nullptr, 1 };
  sg.s[2] = { W1t + 128 * 128, h1b + 128, 256, nullptr, 2 };
  sg.s[3] = { W1t + 192 * 128, h1b + 192, 256, nullptr, 3 };
  sg.s[4] = { Wl1t,            xlb, 64, nullptr, -1 };
  sg.s[5] = { Wr1t,            xrb, 64, bl1,     -1 };
  k_gemm_multi<<<dim3(gx, 3), 256, 0, stream>>>(x, sg, a_src1, a_dst1, es1, ed1, N);

  // ---- GAT1 stats, merged GAT1+SAGE1 aggregate, BN stats+finalize ----
  k_gat_stats4<<<nwb, 256, 0, stream>>>(es1, ed1, row_ptr, csr, alphaE, alphaS, N);
  k_agg_gs1<<<nwb, 256, 0, stream>>>(h1b, xlb, xrb, alphaE, alphaS, row_ptr, csr, b1g, gb, s1b, N);
  k_bn_stats_both<<<512, 256, 0, stream>>>(gb, s1b, statsG, statsS, done,
                                           bn1g_g, bn1g_b, bn1s_g, bn1s_b,
                                           scg, shg, scs, shs, N);

  // ---- GAT layer 2 (BN+ELU on A-load, es2/ed2 epilogue) ----
  k_gemm_bn<<<gx, 256, 0, stream>>>(gb, W2t, scg, shg, a_src2, a_dst2, h2b, es2, ed2, N);
  k_gat_stats1<<<nwb, 256, 0, stream>>>(es2, ed2, row_ptr, csr, alphaE, alphaS, N);
  k_agg_gs2<<<nwb, 256, 0, stream>>>(h2b, s1b, alphaE, alphaS, row_ptr, csr, b2g, scs, shs,
                                     g2b, sagg2b, N);

  // ---- final: fh = relu(g2@Wf1a + sagg2@Wc1 + relu(bn(s1))@Wc2 + biasC) @ Wf2
  k_gemm_final<<<gx, 256, 0, stream>>>(g2b, Wf1at, sagg2b, Wc1t, s1b, Wc2t,
                                       scs, shs, biasC, Wf2, bf2, (float*)d_out, N);
}

// Round 13
// 669.076 us; speedup vs baseline: 1.0799x; 1.0379x over previous
//
#include <hip/hip_runtime.h>
#include <math.h>

// ---------------------------------------------------------------------------
// FraudGCN round 13: exact round-10 measured-best config (670us).
// Reverts round-12's BN finalize fusion (device-wide completion tail stalled
// the dependent GEMM; separate 1-block k_bn_final2 is cheaper).
// Unroll-4 gather walks, paired 2-segment GEMM1, fp16 alphas.
// ---------------------------------------------------------------------------

typedef unsigned short u16;
typedef u16 us4 __attribute__((ext_vector_type(4)));
typedef short s8v __attribute__((ext_vector_type(8)));
typedef float f4v __attribute__((ext_vector_type(4)));

__device__ __forceinline__ float b2f(u16 u) {
  union { unsigned int i; float f; } v; v.i = ((unsigned int)u) << 16; return v.f;
}
__device__ __forceinline__ u16 f2b(float f) {
  union { float f; unsigned int i; } v; v.f = f;
  unsigned int u = v.i;
  return (u16)((u + 0x7fffu + ((u >> 16) & 1u)) >> 16);
}
__device__ __forceinline__ u16 f2h(float f) {
  union { _Float16 h; u16 u; } v; v.h = (_Float16)f; return v.u;
}
__device__ __forceinline__ float h2f(u16 u) {
  union { u16 u; _Float16 h; } v; v.u = u; return (float)v.h;
}

// ---------------- weight prep ----------------
struct WcastDesc { const float* W; u16* Wt; int K; int M; };
struct WPrep {
  WcastDesc d[5];
  const float *Wl2, *Wr2, *bl2, *Wf1, *bf1;
  u16 *Wc1t, *Wc2t;
  float* biasC;
};
__global__ __launch_bounds__(256) void k_wprep(WPrep a) {
  int y = blockIdx.y;
  int idx = blockIdx.x * 256 + threadIdx.x;
  if (y < 5) {
    WcastDesc de = a.d[y];
    int n = de.K * de.M;
    if (idx >= n) return;
    int c = idx / de.K, k = idx - c * de.K;
    de.Wt[idx] = f2b(de.W[(size_t)k * de.M + c]);
  } else {
    if (idx >= 4096) return;
    int m = idx >> 6, k = idx & 63;
    float s1 = 0.f, s2 = 0.f;
    for (int j = 0; j < 64; ++j) {
      float wf = a.Wf1[(size_t)(64 + j) * 64 + m];
      s1 += a.Wl2[k * 64 + j] * wf;
      s2 += a.Wr2[k * 64 + j] * wf;
    }
    a.Wc1t[m * 64 + k] = f2b(s1);
    a.Wc2t[m * 64 + k] = f2b(s2);
    if (k == 0) {
      float b = a.bf1[m];
      for (int j = 0; j < 64; ++j) b += a.bl2[j] * a.Wf1[(size_t)(64 + j) * 64 + m];
      a.biasC[m] = b;
    }
  }
}

// ---------------- CSR build ----------------
__global__ __launch_bounds__(256) void k_deg(const int* __restrict__ ei, int* __restrict__ deg, int E) {
  int e = blockIdx.x * blockDim.x + threadIdx.x;
  if (e < E) atomicAdd(&deg[ei[E + e]], 1);
}

__global__ __launch_bounds__(256) void k_scan1(const int* __restrict__ deg, int* __restrict__ row_ptr,
                                               int* __restrict__ bsum, int n) {
  __shared__ int sh[256];
  int tid = threadIdx.x;
  int i = blockIdx.x * 256 + tid;
  int v = (i < n) ? deg[i] : 0;
  sh[tid] = v;
  __syncthreads();
  for (int off = 1; off < 256; off <<= 1) {
    int t = (tid >= off) ? sh[tid - off] : 0;
    __syncthreads();
    sh[tid] += t;
    __syncthreads();
  }
  if (i < n) row_ptr[i] = sh[tid] - v;
  if (tid == 255) bsum[blockIdx.x] = sh[255];
}

__global__ __launch_bounds__(1024) void k_scan2(int* __restrict__ bsum, int* __restrict__ total, int nb) {
  __shared__ int sh[1024];
  int tid = threadIdx.x;
  int v = (tid < nb) ? bsum[tid] : 0;
  sh[tid] = v;
  __syncthreads();
  for (int off = 1; off < 1024; off <<= 1) {
    int t = (tid >= off) ? sh[tid - off] : 0;
    __syncthreads();
    sh[tid] += t;
    __syncthreads();
  }
  if (tid < nb) bsum[tid] = sh[tid] - v;
  if (tid == 1023) *total = sh[1023];
}

__global__ __launch_bounds__(256) void k_scan3(int* __restrict__ row_ptr, const int* __restrict__ bsum, int n) {
  int i = blockIdx.x * 256 + threadIdx.x;
  if (i < n) row_ptr[i] += bsum[blockIdx.x];
}

__global__ __launch_bounds__(256) void k_scatter(const int* __restrict__ ei, const int* __restrict__ row_ptr,
                                                 int* __restrict__ cursor, int* __restrict__ csr_src, int E) {
  int e = blockIdx.x * blockDim.x + threadIdx.x;
  if (e < E) {
    int d = ei[E + e];
    int pos = row_ptr[d] + atomicAdd(&cursor[d], 1);
    csr_src[pos] = ei[e];
  }
}

// ---------------- paired-segment GEMM (A staged once per pair) --------------
struct Seg { const u16* Wt; u16* out; int ldout; const float* bias; int head; };
struct Segs6 { Seg s[6]; };
__global__ __launch_bounds__(256) void k_gemm_multi(const float* __restrict__ X, Segs6 sg,
                                                    const float* __restrict__ a_src1, const float* __restrict__ a_dst1,
                                                    float* __restrict__ es1, float* __restrict__ ed1, int Nrows) {
  Seg segA = sg.s[blockIdx.y * 2 + 0];
  Seg segB = sg.s[blockIdx.y * 2 + 1];
  __shared__ u16 As[64][40];
  __shared__ u16 Bs[2][64][40];
  int row0 = blockIdx.x * 64;
  int tid = threadIdx.x;
  int w = tid >> 6, lane = tid & 63;
  int lr = tid >> 2;
  int lseg = (tid & 3) * 8;
  f4v acc[2][4];
#pragma unroll
  for (int p = 0; p < 2; ++p)
#pragma unroll
    for (int nn = 0; nn < 4; ++nn) acc[p][nn] = (f4v){0.f, 0.f, 0.f, 0.f};
  int ar = (w << 4) + (lane & 15);
  int ak = (lane >> 4) << 3;

  for (int k0 = 0; k0 < 128; k0 += 32) {
    __syncthreads();
    int gr = row0 + lr;
    s8v av = {};
    if (gr < Nrows) {
      float4 lo = *reinterpret_cast<const float4*>(X + (size_t)gr * 128 + k0 + lseg);
      float4 hi = *reinterpret_cast<const float4*>(X + (size_t)gr * 128 + k0 + lseg + 4);
      av[0] = (short)f2b(lo.x); av[1] = (short)f2b(lo.y); av[2] = (short)f2b(lo.z); av[3] = (short)f2b(lo.w);
      av[4] = (short)f2b(hi.x); av[5] = (short)f2b(hi.y); av[6] = (short)f2b(hi.z); av[7] = (short)f2b(hi.w);
    }
    *reinterpret_cast<s8v*>(&As[lr][lseg]) = av;
    s8v bva = *reinterpret_cast<const s8v*>(segA.Wt + (size_t)lr * 128 + k0 + lseg);
    *reinterpret_cast<s8v*>(&Bs[0][lr][lseg]) = bva;
    s8v bvb = *reinterpret_cast<const s8v*>(segB.Wt + (size_t)lr * 128 + k0 + lseg);
    *reinterpret_cast<s8v*>(&Bs[1][lr][lseg]) = bvb;
    __syncthreads();
    s8v af = *reinterpret_cast<const s8v*>(&As[ar][ak]);
#pragma unroll
    for (int p = 0; p < 2; ++p) {
#pragma unroll
      for (int nn = 0; nn < 4; ++nn) {
        s8v bf = *reinterpret_cast<const s8v*>(&Bs[p][(nn << 4) + (lane & 15)][ak]);
        acc[p][nn] = __builtin_amdgcn_mfma_f32_16x16x32_bf16(af, bf, acc[p][nn], 0, 0, 0);
      }
    }
  }
  int r0 = row0 + (w << 4) + ((lane >> 4) << 2);
  int cc = lane & 15;
#pragma unroll
  for (int p = 0; p < 2; ++p) {
    Seg seg = p ? segB : segA;
#pragma unroll
    for (int nn = 0; nn < 4; ++nn) {
      int gc = (nn << 4) + cc;
      float bv = seg.bias ? seg.bias[gc] : 0.f;
#pragma unroll
      for (int j = 0; j < 4; ++j) {
        int gr = r0 + j;
        if (gr < Nrows) seg.out[(size_t)gr * seg.ldout + gc] = f2b(acc[p][nn][j] + bv);
      }
    }
    if (seg.head >= 0) {
      int s = seg.head;
      float pe[4] = {0.f, 0.f, 0.f, 0.f}, pd[4] = {0.f, 0.f, 0.f, 0.f};
#pragma unroll
      for (int nn = 0; nn < 4; ++nn) {
        int col = (nn << 4) + cc;
        float asv = a_src1[s * 64 + col];
        float adv = a_dst1[s * 64 + col];
#pragma unroll
        for (int j = 0; j < 4; ++j) {
          pe[j] += acc[p][nn][j] * asv;
          pd[j] += acc[p][nn][j] * adv;
        }
      }
#pragma unroll
      for (int off = 1; off < 16; off <<= 1) {
#pragma unroll
        for (int j = 0; j < 4; ++j) {
          pe[j] += __shfl_xor(pe[j], off, 64);
          pd[j] += __shfl_xor(pd[j], off, 64);
        }
      }
      if (cc == 0) {
#pragma unroll
        for (int j = 0; j < 4; ++j) {
          int gr = r0 + j;
          if (gr < Nrows) {
            es1[(size_t)gr * 4 + s] = pe[j];
            ed1[(size_t)gr * 4 + s] = pd[j];
          }
        }
      }
    }
  }
}

// ---------------- GAT2 GEMM: BN+ELU on A-load, es2/ed2 epilogue --------------
__global__ __launch_bounds__(256) void k_gemm_bn(const u16* __restrict__ A, const u16* __restrict__ Wt,
                                                 const float* __restrict__ sc, const float* __restrict__ sh,
                                                 const float* __restrict__ a_src2, const float* __restrict__ a_dst2,
                                                 u16* __restrict__ C, float* __restrict__ es2,
                                                 float* __restrict__ ed2, int Nrows) {
  __shared__ u16 As[64][40];
  __shared__ u16 Bs[64][40];
  int row0 = blockIdx.x * 64;
  int tid = threadIdx.x;
  int w = tid >> 6, lane = tid & 63;
  int lr = tid >> 2;
  int lseg = (tid & 3) * 8;
  f4v acc[4];
#pragma unroll
  for (int nn = 0; nn < 4; ++nn) acc[nn] = (f4v){0.f, 0.f, 0.f, 0.f};
  int ar = (w << 4) + (lane & 15);
  int ak = (lane >> 4) << 3;

  for (int k0 = 0; k0 < 256; k0 += 32) {
    __syncthreads();
    int gr = row0 + lr;
    s8v av = {};
    if (gr < Nrows) {
      av = *reinterpret_cast<const s8v*>(A + (size_t)gr * 256 + k0 + lseg);
#pragma unroll
      for (int j = 0; j < 8; ++j) {
        int c = k0 + lseg + j;
        float a = b2f((u16)av[j]) * sc[c] + sh[c];
        a = (a > 0.f) ? a : (__expf(a) - 1.f);
        av[j] = (short)f2b(a);
      }
    }
    *reinterpret_cast<s8v*>(&As[lr][lseg]) = av;
    s8v bv = *reinterpret_cast<const s8v*>(Wt + (size_t)lr * 256 + k0 + lseg);
    *reinterpret_cast<s8v*>(&Bs[lr][lseg]) = bv;
    __syncthreads();
    s8v af = *reinterpret_cast<const s8v*>(&As[ar][ak]);
#pragma unroll
    for (int nn = 0; nn < 4; ++nn) {
      s8v bf = *reinterpret_cast<const s8v*>(&Bs[(nn << 4) + (lane & 15)][ak]);
      acc[nn] = __builtin_amdgcn_mfma_f32_16x16x32_bf16(af, bf, acc[nn], 0, 0, 0);
    }
  }
  int r0 = row0 + (w << 4) + ((lane >> 4) << 2);
  int cc = lane & 15;
  float pe[4] = {0.f, 0.f, 0.f, 0.f}, pd[4] = {0.f, 0.f, 0.f, 0.f};
#pragma unroll
  for (int nn = 0; nn < 4; ++nn) {
    int gc = (nn << 4) + cc;
    float asv = a_src2[gc], adv = a_dst2[gc];
#pragma unroll
    for (int j = 0; j < 4; ++j) {
      float hv = acc[nn][j];
      pe[j] += hv * asv;
      pd[j] += hv * adv;
      int gr = r0 + j;
      if (gr < Nrows) C[(size_t)gr * 64 + gc] = f2b(hv);
    }
  }
#pragma unroll
  for (int off = 1; off < 16; off <<= 1) {
#pragma unroll
    for (int j = 0; j < 4; ++j) {
      pe[j] += __shfl_xor(pe[j], off, 64);
      pd[j] += __shfl_xor(pd[j], off, 64);
    }
  }
  if (cc == 0) {
#pragma unroll
    for (int j = 0; j < 4; ++j) {
      int gr = r0 + j;
      if (gr < Nrows) { es2[gr] = pe[j]; ed2[gr] = pd[j]; }
    }
  }
}

// ---------------- GAT softmax stats + fp16 alphas ----------------
__global__ __launch_bounds__(256) void k_gat_stats4(const float* __restrict__ es, const float* __restrict__ ed,
                                                    const int* __restrict__ row_ptr, const int* __restrict__ csr,
                                                    u16* __restrict__ alphaE, u16* __restrict__ alphaS, int n) {
  int wid = (blockIdx.x * blockDim.x + threadIdx.x) >> 6;
  int lane = threadIdx.x & 63;
  if (wid >= n) return;
  int start = row_ptr[wid];
  int deg = row_ptr[wid + 1] - start;
  int h = lane & 3, esl = lane >> 2;
  float edst = ed[(size_t)wid * 4 + h];

  float m = -1e30f, s = 0.f;
  for (int e = esl; e < deg + 1; e += 16) {
    int sn = (e < deg) ? csr[start + e] : wid;
    float v = es[(size_t)sn * 4 + h] + edst;
    v = (v >= 0.f) ? v : 0.2f * v;
    if (v > m) { s = s * __expf(m - v) + 1.f; m = v; }
    else s += __expf(v - m);
  }
#pragma unroll
  for (int off = 4; off < 64; off <<= 1) {
    float mo = __shfl_xor(m, off, 64);
    float so = __shfl_xor(s, off, 64);
    float M = fmaxf(m, mo);
    s = s * __expf(m - M) + so * __expf(mo - M);
    m = M;
  }
  float invS = 1.f / s;
  for (int e = esl; e < deg + 1; e += 16) {
    int sn = (e < deg) ? csr[start + e] : wid;
    float v = es[(size_t)sn * 4 + h] + edst;
    v = (v >= 0.f) ? v : 0.2f * v;
    u16 a = f2h(__expf(v - m) * invS);
    if (e < deg) alphaE[(size_t)(start + e) * 4 + h] = a;
    else alphaS[(size_t)wid * 4 + h] = a;
  }
}

__global__ __launch_bounds__(256) void k_gat_stats1(const float* __restrict__ es, const float* __restrict__ ed,
                                                    const int* __restrict__ row_ptr, const int* __restrict__ csr,
                                                    u16* __restrict__ alphaE, u16* __restrict__ alphaS, int n) {
  int wid = (blockIdx.x * blockDim.x + threadIdx.x) >> 6;
  int lane = threadIdx.x & 63;
  if (wid >= n) return;
  int start = row_ptr[wid];
  int deg = row_ptr[wid + 1] - start;
  float edst = ed[wid];
  float m = -1e30f, s = 0.f;
  for (int e = lane; e < deg + 1; e += 64) {
    int sn = (e < deg) ? csr[start + e] : wid;
    float v = es[sn] + edst;
    v = (v >= 0.f) ? v : 0.2f * v;
    if (v > m) { s = s * __expf(m - v) + 1.f; m = v; }
    else s += __expf(v - m);
  }
#pragma unroll
  for (int off = 1; off < 64; off <<= 1) {
    float mo = __shfl_xor(m, off, 64);
    float so = __shfl_xor(s, off, 64);
    float M = fmaxf(m, mo);
    s = s * __expf(m - M) + so * __expf(mo - M);
    m = M;
  }
  float invS = 1.f / s;
  for (int e = lane; e < deg + 1; e += 64) {
    int sn = (e < deg) ? csr[start + e] : wid;
    float v = es[sn] + edst;
    v = (v >= 0.f) ? v : 0.2f * v;
    u16 a = f2h(__expf(v - m) * invS);
    if (e < deg) alphaE[start + e] = a;
    else alphaS[wid] = a;
  }
}

// ---------------- merged GAT1 + SAGE1 aggregate (unroll 4) ------------------
__global__ __launch_bounds__(256) void k_agg_gs1(const u16* __restrict__ h1, const u16* __restrict__ xl,
                                                 const u16* __restrict__ xr, const u16* __restrict__ alphaE,
                                                 const u16* __restrict__ alphaS, const int* __restrict__ row_ptr,
                                                 const int* __restrict__ csr, const float* __restrict__ b1g,
                                                 u16* __restrict__ gb, u16* __restrict__ s1, int n) {
  int wid = (blockIdx.x * blockDim.x + threadIdx.x) >> 6;
  int lane = threadIdx.x & 63;
  if (wid >= n) return;
  int start = row_ptr[wid];
  int deg = row_ptr[wid + 1] - start;
  int hl = lane >> 4;

  float accG[4];
  float accS = 0.f;
  {
    float aS = h2f(alphaS[(size_t)wid * 4 + hl]);
    us4 hv = *(reinterpret_cast<const us4*>(h1 + (size_t)wid * 256) + lane);
#pragma unroll
    for (int j = 0; j < 4; ++j) accG[j] = aS * b2f(hv[j]);
  }

  int e = 0;
  for (; e + 4 <= deg; e += 4) {
    int sn[4];
    float al[4];
#pragma unroll
    for (int i = 0; i < 4; ++i) {
      sn[i] = csr[start + e + i];
      al[i] = h2f(alphaE[(size_t)(start + e + i) * 4 + hl]);
    }
#pragma unroll
    for (int i = 0; i < 4; ++i) {
      us4 hv = *(reinterpret_cast<const us4*>(h1 + (size_t)sn[i] * 256) + lane);
#pragma unroll
      for (int j = 0; j < 4; ++j) accG[j] += al[i] * b2f(hv[j]);
      accS += b2f(xl[(size_t)sn[i] * 64 + lane]);
    }
  }
  for (; e < deg; ++e) {
    int sn = csr[start + e];
    float al = h2f(alphaE[(size_t)(start + e) * 4 + hl]);
    us4 hv = *(reinterpret_cast<const us4*>(h1 + (size_t)sn * 256) + lane);
#pragma unroll
    for (int j = 0; j < 4; ++j) accG[j] += al * b2f(hv[j]);
    accS += b2f(xl[(size_t)sn * 64 + lane]);
  }

  int c0 = lane * 4;
#pragma unroll
  for (int j = 0; j < 4; ++j) gb[(size_t)wid * 256 + c0 + j] = f2b(accG[j] + b1g[c0 + j]);
  float inv = 1.f / fmaxf((float)deg, 1.f);
  s1[(size_t)wid * 64 + lane] = f2b(accS * inv + b2f(xr[(size_t)wid * 64 + lane]));
}

// ---------------- merged GAT2 + SAGE2 aggregate (unroll 4) ------------------
__global__ __launch_bounds__(256) void k_agg_gs2(const u16* __restrict__ h2, const u16* __restrict__ s1,
                                                 const u16* __restrict__ alphaE, const u16* __restrict__ alphaS,
                                                 const int* __restrict__ row_ptr, const int* __restrict__ csr,
                                                 const float* __restrict__ b2g, const float* __restrict__ scs,
                                                 const float* __restrict__ shs, u16* __restrict__ g2,
                                                 u16* __restrict__ sagg2, int n) {
  int wid = (blockIdx.x * blockDim.x + threadIdx.x) >> 6;
  int lane = threadIdx.x & 63;
  if (wid >= n) return;
  int start = row_ptr[wid];
  int deg = row_ptr[wid + 1] - start;
  float scv = scs[lane], shv = shs[lane];

  float accG = h2f(alphaS[wid]) * b2f(h2[(size_t)wid * 64 + lane]);
  float accS = 0.f;
  int e = 0;
  for (; e + 4 <= deg; e += 4) {
    int sn[4];
    float al[4];
#pragma unroll
    for (int i = 0; i < 4; ++i) {
      sn[i] = csr[start + e + i];
      al[i] = h2f(alphaE[start + e + i]);
    }
#pragma unroll
    for (int i = 0; i < 4; ++i) {
      accG += al[i] * b2f(h2[(size_t)sn[i] * 64 + lane]);
      accS += fmaxf(b2f(s1[(size_t)sn[i] * 64 + lane]) * scv + shv, 0.f);
    }
  }
  for (; e < deg; ++e) {
    int sn = csr[start + e];
    accG += h2f(alphaE[start + e]) * b2f(h2[(size_t)sn * 64 + lane]);
    accS += fmaxf(b2f(s1[(size_t)sn * 64 + lane]) * scv + shv, 0.f);
  }

  g2[(size_t)wid * 64 + lane] = f2b(accG + b2g[lane]);
  float inv = 1.f / fmaxf((float)deg, 1.f);
  sagg2[(size_t)wid * 64 + lane] = f2b(accS * inv);
}

// ---------------- merged BN stats: gb (256ch) + s1 (64ch) -------------------
__global__ __launch_bounds__(256) void k_bn_stats_both(const u16* __restrict__ gb, const u16* __restrict__ s1,
                                                       float* __restrict__ statsG, float* __restrict__ statsS,
                                                       int n) {
  int tid = threadIdx.x;
  __shared__ float ls[256], lq[256];
  if (blockIdx.x < 256) {
    int c = tid;
    float s = 0.f, q = 0.f;
    for (int r = blockIdx.x; r < n; r += 256) {
      float v = b2f(gb[(size_t)r * 256 + c]);
      s += v;
      q += v * v;
    }
    atomicAdd(&statsG[c], s);
    atomicAdd(&statsG[256 + c], q);
  } else {
    int bx = blockIdx.x - 256;
    int c = tid & 63;
    int rsub = tid >> 6;
    float s = 0.f, q = 0.f;
    for (int r = bx * 4 + rsub; r < n; r += 256 * 4) {
      float v = b2f(s1[(size_t)r * 64 + c]);
      s += v;
      q += v * v;
    }
    ls[tid] = s; lq[tid] = q;
    __syncthreads();
    if (tid < 64) {
#pragma unroll
      for (int i = 1; i < 4; ++i) { s += ls[tid + i * 64]; q += lq[tid + i * 64]; }
      atomicAdd(&statsS[c], s);
      atomicAdd(&statsS[64 + c], q);
    }
  }
}

__global__ __launch_bounds__(256) void k_bn_final2(const float* __restrict__ statsG, const float* __restrict__ statsS,
                                                   const float* __restrict__ gG, const float* __restrict__ bG,
                                                   const float* __restrict__ gS, const float* __restrict__ bS,
                                                   float* __restrict__ scG, float* __restrict__ shG,
                                                   float* __restrict__ scS, float* __restrict__ shS, int n) {
  int c = threadIdx.x;
  float invn = 1.f / (float)n;
  {
    float mu = statsG[c] * invn;
    float var = statsG[256 + c] * invn - mu * mu;
    float rs = rsqrtf(var + 1e-5f) * gG[c];
    scG[c] = rs;
    shG[c] = bG[c] - mu * rs;
  }
  if (c < 64) {
    float mu = statsS[c] * invn;
    float var = statsS[64 + c] * invn - mu * mu;
    float rs = rsqrtf(var + 1e-5f) * gS[c];
    scS[c] = rs;
    shS[c] = bS[c] - mu * rs;
  }
}

// ---------------- final GEMM: 3 inputs (A3 gets BN+relu) + fused head --------
__global__ __launch_bounds__(256) void k_gemm_final(const u16* __restrict__ A1, const u16* __restrict__ W1,
                                                    const u16* __restrict__ A2, const u16* __restrict__ W2,
                                                    const u16* __restrict__ A3, const u16* __restrict__ W3,
                                                    const float* __restrict__ scS, const float* __restrict__ shS,
                                                    const float* __restrict__ biasC, const float* __restrict__ Wf2,
                                                    const float* __restrict__ bf2, float* __restrict__ out,
                                                    int Nrows) {
  __shared__ u16 As[64][40];
  __shared__ u16 Bs[64][40];
  int row0 = blockIdx.x * 64;
  int tid = threadIdx.x;
  int w = tid >> 6, lane = tid & 63;
  int lr = tid >> 2;
  int lseg = (tid & 3) * 8;
  f4v acc[4];
#pragma unroll
  for (int nn = 0; nn < 4; ++nn) acc[nn] = (f4v){0.f, 0.f, 0.f, 0.f};
  int ar = (w << 4) + (lane & 15);
  int ak = (lane >> 4) << 3;

  const u16* Aarr[3] = {A1, A2, A3};
  const u16* Warr[3] = {W1, W2, W3};
#pragma unroll
  for (int ph = 0; ph < 3; ++ph) {
    const u16* A = Aarr[ph];
    const u16* Wt = Warr[ph];
#pragma unroll
    for (int k0 = 0; k0 < 64; k0 += 32) {
      __syncthreads();
      int gr = row0 + lr;
      s8v av = {};
      if (gr < Nrows) {
        av = *reinterpret_cast<const s8v*>(A + (size_t)gr * 64 + k0 + lseg);
        if (ph == 2) {
#pragma unroll
          for (int j = 0; j < 8; ++j) {
            int c = k0 + lseg + j;
            float a = fmaxf(b2f((u16)av[j]) * scS[c] + shS[c], 0.f);
            av[j] = (short)f2b(a);
          }
        }
      }
      *reinterpret_cast<s8v*>(&As[lr][lseg]) = av;
      s8v bv = *reinterpret_cast<const s8v*>(Wt + (size_t)lr * 64 + k0 + lseg);
      *reinterpret_cast<s8v*>(&Bs[lr][lseg]) = bv;
      __syncthreads();
      s8v af = *reinterpret_cast<const s8v*>(&As[ar][ak]);
#pragma unroll
      for (int nn = 0; nn < 4; ++nn) {
        s8v bf = *reinterpret_cast<const s8v*>(&Bs[(nn << 4) + (lane & 15)][ak]);
        acc[nn] = __builtin_amdgcn_mfma_f32_16x16x32_bf16(af, bf, acc[nn], 0, 0, 0);
      }
    }
  }

  int r0 = row0 + (w << 4) + ((lane >> 4) << 2);
  int cc = lane & 15;
  float p0[4] = {0.f, 0.f, 0.f, 0.f}, p1[4] = {0.f, 0.f, 0.f, 0.f};
#pragma unroll
  for (int nn = 0; nn < 4; ++nn) {
    int col = (nn << 4) + cc;
    float bC = biasC[col];
    float w0 = Wf2[col * 2 + 0], w1 = Wf2[col * 2 + 1];
#pragma unroll
    for (int j = 0; j < 4; ++j) {
      float f = fmaxf(acc[nn][j] + bC, 0.f);
      p0[j] += f * w0;
      p1[j] += f * w1;
    }
  }
#pragma unroll
  for (int off = 1; off < 16; off <<= 1) {
#pragma unroll
    for (int j = 0; j < 4; ++j) {
      p0[j] += __shfl_xor(p0[j], off, 64);
      p1[j] += __shfl_xor(p1[j], off, 64);
    }
  }
  if (cc == 0) {
    float b0 = bf2[0], b1 = bf2[1];
#pragma unroll
    for (int j = 0; j < 4; ++j) {
      int gr = r0 + j;
      if (gr < Nrows) {
        out[(size_t)gr * 2 + 0] = p0[j] + b0;
        out[(size_t)gr * 2 + 1] = p1[j] + b1;
      }
    }
  }
}

// ---------------------------------------------------------------------------
extern "C" void kernel_launch(void* const* d_in, const int* in_sizes, int n_in,
                              void* d_out, int out_size, void* d_ws, size_t ws_size,
                              hipStream_t stream) {
  const float* x      = (const float*)d_in[0];
  const int*   ei     = (const int*)d_in[1];
  const float* W1g    = (const float*)d_in[2];
  const float* a_src1 = (const float*)d_in[3];
  const float* a_dst1 = (const float*)d_in[4];
  const float* b1g    = (const float*)d_in[5];
  const float* bn1g_g = (const float*)d_in[6];
  const float* bn1g_b = (const float*)d_in[7];
  const float* W2g    = (const float*)d_in[8];
  const float* a_src2 = (const float*)d_in[9];
  const float* a_dst2 = (const float*)d_in[10];
  const float* b2g    = (const float*)d_in[11];
  const float* Wl1    = (const float*)d_in[12];
  const float* bl1    = (const float*)d_in[13];
  const float* Wr1    = (const float*)d_in[14];
  const float* bn1s_g = (const float*)d_in[15];
  const float* bn1s_b = (const float*)d_in[16];
  const float* Wl2    = (const float*)d_in[17];
  const float* bl2    = (const float*)d_in[18];
  const float* Wr2    = (const float*)d_in[19];
  const float* Wf1    = (const float*)d_in[20];
  const float* bf1    = (const float*)d_in[21];
  const float* Wf2    = (const float*)d_in[22];
  const float* bf2    = (const float*)d_in[23];

  const int N = in_sizes[0] / 128;  // 100000
  const int E = in_sizes[1] / 2;    // 1600000

  char* ws = (char*)d_ws;
  size_t off = 0;
  auto alloc = [&](size_t bytes) -> void* {
    size_t o = (off + 255) & ~(size_t)255;
    off = o + bytes;
    return (void*)(ws + o);
  };

  u16* h1b   = (u16*)alloc((size_t)N * 256 * 2);   // sagg2b overlays after agg_gs1
  u16* gb    = (u16*)alloc((size_t)N * 256 * 2);
  u16* h2b   = (u16*)alloc((size_t)N * 64 * 2);
  u16* g2b   = (u16*)alloc((size_t)N * 64 * 2);
  u16* xlb   = (u16*)alloc((size_t)N * 64 * 2);
  u16* xrb   = (u16*)alloc((size_t)N * 64 * 2);
  u16* s1b   = (u16*)alloc((size_t)N * 64 * 2);
  float* es1 = (float*)alloc((size_t)N * 4 * 4);
  float* ed1 = (float*)alloc((size_t)N * 4 * 4);
  float* es2 = (float*)alloc((size_t)N * 4);
  float* ed2 = (float*)alloc((size_t)N * 4);
  u16* alphaE = (u16*)alloc((size_t)E * 4 * 2);
  u16* alphaS = (u16*)alloc((size_t)N * 4 * 2);
  int* deg     = (int*)alloc((size_t)N * 2 * 4);
  int* cursor  = deg + N;
  int* row_ptr = (int*)alloc((size_t)(N + 1) * 4);
  int* bsum    = (int*)alloc(1024 * 4);
  int* csr     = (int*)alloc((size_t)E * 4);
  float* statsG = (float*)alloc((512 + 128) * 4);
  float* statsS = statsG + 512;
  float* scg   = (float*)alloc(256 * 4);
  float* shg   = (float*)alloc(256 * 4);
  float* scs   = (float*)alloc(64 * 4);
  float* shs   = (float*)alloc(64 * 4);
  float* biasC = (float*)alloc(64 * 4);
  u16* W1t  = (u16*)alloc(256 * 128 * 2);
  u16* W2t  = (u16*)alloc(64 * 256 * 2);
  u16* Wl1t = (u16*)alloc(64 * 128 * 2);
  u16* Wr1t = (u16*)alloc(64 * 128 * 2);
  u16* Wf1at= (u16*)alloc(64 * 64 * 2);
  u16* Wc1t = (u16*)alloc(64 * 64 * 2);
  u16* Wc2t = (u16*)alloc(64 * 64 * 2);
  u16* sagg2b = h1b;  // overlay: h1b dead after agg_gs1

  const int tb = 256;
  const int nwb = (N + 3) / 4;
  const int nsb = (N + 255) / 256;
  const int gx = (N + 63) / 64;

  // ---- CSR build + zeroing ----
  hipMemsetAsync(deg, 0, (size_t)N * 2 * 4, stream);
  hipMemsetAsync(statsG, 0, (512 + 128) * 4, stream);
  k_deg<<<(E + tb - 1) / tb, tb, 0, stream>>>(ei, deg, E);
  k_scan1<<<nsb, 256, 0, stream>>>(deg, row_ptr, bsum, N);
  k_scan2<<<1, 1024, 0, stream>>>(bsum, row_ptr + N, nsb);
  k_scan3<<<nsb, 256, 0, stream>>>(row_ptr, bsum, N);
  k_scatter<<<(E + tb - 1) / tb, tb, 0, stream>>>(ei, row_ptr, cursor, csr, E);

  // ---- weight prep ----
  WPrep wp;
  wp.d[0] = { W1g, W1t, 128, 256 };
  wp.d[1] = { W2g, W2t, 256, 64 };
  wp.d[2] = { Wl1, Wl1t, 128, 64 };
  wp.d[3] = { Wr1, Wr1t, 128, 64 };
  wp.d[4] = { Wf1, Wf1at, 64, 64 };
  wp.Wl2 = Wl2; wp.Wr2 = Wr2; wp.bl2 = bl2; wp.Wf1 = Wf1; wp.bf1 = bf1;
  wp.Wc1t = Wc1t; wp.Wc2t = Wc2t; wp.biasC = biasC;
  dim3 wgrid((128 * 256 + tb - 1) / tb, 6);
  k_wprep<<<wgrid, tb, 0, stream>>>(wp);

  // ---- paired-segment GEMM: (h1 heads 0-1 | 2-3 | xl,xr); es1/ed1 fused ----
  Segs6 sg;
  sg.s[0] = { W1t,             h1b + 0,   256, nullptr, 0 };
  sg.s[1] = { W1t + 64 * 128,  h1b + 64,  256, nullptr, 1 };
  sg.s[2] = { W1t + 128 * 128, h1b + 128, 256, nullptr, 2 };
  sg.s[3] = { W1t + 192 * 128, h1b + 192, 256, nullptr, 3 };
  sg.s[4] = { Wl1t,            xlb, 64, nullptr, -1 };
  sg.s[5] = { Wr1t,            xrb, 64, bl1,     -1 };
  k_gemm_multi<<<dim3(gx, 3), 256, 0, stream>>>(x, sg, a_src1, a_dst1, es1, ed1, N);

  // ---- GAT1 stats, merged GAT1+SAGE1 aggregate ----
  k_gat_stats4<<<nwb, 256, 0, stream>>>(es1, ed1, row_ptr, csr, alphaE, alphaS, N);
  k_agg_gs1<<<nwb, 256, 0, stream>>>(h1b, xlb, xrb, alphaE, alphaS, row_ptr, csr, b1g, gb, s1b, N);
  k_bn_stats_both<<<512, 256, 0, stream>>>(gb, s1b, statsG, statsS, N);
  k_bn_final2<<<1, 256, 0, stream>>>(statsG, statsS, bn1g_g, bn1g_b, bn1s_g, bn1s_b,
                                     scg, shg, scs, shs, N);

  // ---- GAT layer 2 (BN+ELU on A-load, es2/ed2 epilogue) ----
  k_gemm_bn<<<gx, 256, 0, stream>>>(gb, W2t, scg, shg, a_src2, a_dst2, h2b, es2, ed2, N);
  k_gat_stats1<<<nwb, 256, 0, stream>>>(es2, ed2, row_ptr, csr, alphaE, alphaS, N);
  k_agg_gs2<<<nwb, 256, 0, stream>>>(h2b, s1b, alphaE, alphaS, row_ptr, csr, b2g, scs, shs,
                                     g2b, sagg2b, N);

  // ---- final: fh = relu(g2@Wf1a + sagg2@Wc1 + relu(bn(s1))@Wc2 + biasC) @ Wf2
  k_gemm_final<<<gx, 256, 0, stream>>>(g2b, Wf1at, sagg2b, Wc1t, s1b, Wc2t,
                                       scs, shs, biasC, Wf2, bf2, (float*)d_out, N);
}